// Round 1
// baseline (6476.214 us; speedup 1.0000x reference)
//
#include <hip/hip_runtime.h>
#include <math.h>

// ---- problem constants -------------------------------------------------
#define HID   768
#define SEQ   512
#define BATCH 8
#define LAYERS 8
#define VOC   10000
#define NROWS (BATCH*SEQ)            // 4096
#define NH    ((long long)NROWS*HID) // 3,145,728 floats per [B,S,H] buffer
#define EPSLN 1e-5f

// ---- embedding + positional encoding -----------------------------------
__global__ __launch_bounds__(256) void embed_kernel(
    const int* __restrict__ x, const float* __restrict__ emb,
    float* __restrict__ Z)
{
    const int row = blockIdx.x;          // b*SEQ + s
    const int s   = row & (SEQ - 1);
    const int tok = x[row];
    const long long base  = (long long)row * HID;
    const long long ebase = (long long)tok * HID;
    // -2*ln(10000)/768
    const float coef = -0.0239852613853544f;
    #pragma unroll
    for (int j = 0; j < 3; ++j) {
        const int h = threadIdx.x + 256 * j;
        const int i = h >> 1;
        const float div = expf((float)i * coef);
        const float ang = (float)s * div;
        const float pe  = (h & 1) ? cosf(ang) : sinf(ang);
        Z[base + h] = emb[ebase + h] + pe;
    }
}

// ---- generic fp32 GEMM: C = alpha*(A @ B) + bias, optional relu ---------
// A: [M,K] row-major. B: TRANSB ? [N,K] : [K,N], row-major. C: [M,N].
// blockIdx.z = batch (strides sA/sB/sC in elements).
template<bool TRANSB, bool RELU>
__global__ __launch_bounds__(256) void gemm_f32(
    const float* __restrict__ A, int lda, long long sA,
    const float* __restrict__ Bm, int ldb, long long sB,
    float* __restrict__ C, int ldc, long long sC,
    int M, int N, int K,
    const float* __restrict__ bias, float alpha)
{
    __shared__ float As[16][68];
    __shared__ float Bs[16][68];
    const int bz = blockIdx.z;
    A  += sA * bz;  Bm += sB * bz;  C += sC * bz;
    const int n0 = blockIdx.x * 64;
    const int m0 = blockIdx.y * 64;
    const int t  = threadIdx.x;
    const int tk = t & 15, trow = t >> 4;   // [16k x 16row] loader layout
    const int nb = t & 63, kb = t >> 6;     // [4k x 64n] loader layout
    const int tm4 = (t & 15) * 4, tn4 = (t >> 4) * 4;
    float acc[4][4] = {};

    for (int k0 = 0; k0 < K; k0 += 16) {
        #pragma unroll
        for (int p = 0; p < 4; ++p) {
            const int m = trow + 16 * p;     // M always multiple of 64 here
            As[tk][m] = A[(long long)(m0 + m) * lda + (k0 + tk)];
        }
        if (TRANSB) {
            #pragma unroll
            for (int p = 0; p < 4; ++p) {
                const int n = trow + 16 * p;
                float v = 0.f;
                if (n0 + n < N) v = Bm[(long long)(n0 + n) * ldb + (k0 + tk)];
                Bs[tk][n] = v;
            }
        } else {
            #pragma unroll
            for (int p = 0; p < 4; ++p) {
                const int k = kb + 4 * p;
                float v = 0.f;
                if (n0 + nb < N) v = Bm[(long long)(k0 + k) * ldb + (n0 + nb)];
                Bs[k][nb] = v;
            }
        }
        __syncthreads();
        #pragma unroll
        for (int kk = 0; kk < 16; ++kk) {
            const float4 a4 = *(const float4*)&As[kk][tm4];
            const float4 b4 = *(const float4*)&Bs[kk][tn4];
            const float a[4] = {a4.x, a4.y, a4.z, a4.w};
            const float b[4] = {b4.x, b4.y, b4.z, b4.w};
            #pragma unroll
            for (int i = 0; i < 4; ++i)
                #pragma unroll
                for (int j = 0; j < 4; ++j)
                    acc[i][j] = fmaf(a[i], b[j], acc[i][j]);
        }
        __syncthreads();
    }

    float bv[4] = {0.f, 0.f, 0.f, 0.f};
    if (bias) {
        #pragma unroll
        for (int j = 0; j < 4; ++j)
            if (n0 + tn4 + j < N) bv[j] = bias[n0 + tn4 + j];
    }
    const bool full = (n0 + 64) <= N;
    #pragma unroll
    for (int i = 0; i < 4; ++i) {
        const long long crow = (long long)(m0 + tm4 + i) * ldc + n0 + tn4;
        float o[4];
        #pragma unroll
        for (int j = 0; j < 4; ++j) {
            float v = alpha * acc[i][j] + bv[j];
            if (RELU) v = fmaxf(v, 0.f);
            o[j] = v;
        }
        if (full) {
            *(float4*)&C[crow] = make_float4(o[0], o[1], o[2], o[3]);
        } else {
            #pragma unroll
            for (int j = 0; j < 4; ++j)
                if (n0 + tn4 + j < N) C[crow + j] = o[j];
        }
    }
}

// ---- masked softmax over the QUERY axis (dim=1), in place ---------------
// att[b,q,k]; for fixed (b,k): softmax over q where (k<=q && q<len && k<len),
// masked-out entries become 0. Block: 256 = 4(q-slice) x 64(k). Grid (B, S/64).
__global__ __launch_bounds__(256) void softmax_q_kernel(
    float* __restrict__ att, const int* __restrict__ lengths)
{
    const int b  = blockIdx.x;
    const int k0 = blockIdx.y * 64;
    const int tx = threadIdx.x & 63;
    const int ty = threadIdx.x >> 6;   // 0..3
    const int c  = k0 + tx;
    const int len = lengths[b];
    float* base = att + (long long)b * SEQ * SEQ;
    const bool cvalid = (c < len);

    float m = -3.0e38f, ssum = 0.f;
    for (int q = ty; q < SEQ; q += 4) {
        if (cvalid && c <= q && q < len) {
            const float xv = base[(long long)q * SEQ + c];
            if (xv > m) { ssum = ssum * __expf(m - xv) + 1.f; m = xv; }
            else        { ssum += __expf(xv - m); }
        }
    }
    __shared__ float ms[4][64], ss[4][64];
    ms[ty][tx] = m; ss[ty][tx] = ssum;
    __syncthreads();
    if (ty == 0) {
        float M = ms[0][tx];
        #pragma unroll
        for (int r = 1; r < 4; ++r) M = fmaxf(M, ms[r][tx]);
        float Sx = 0.f;
        #pragma unroll
        for (int r = 0; r < 4; ++r) Sx += ss[r][tx] * __expf(ms[r][tx] - M);
        ms[0][tx] = M; ss[0][tx] = Sx;
    }
    __syncthreads();
    const float M   = ms[0][tx];
    const float den = ss[0][tx];
    const float inv = (den > 0.f) ? 1.f / den : 0.f;
    for (int q = ty; q < SEQ; q += 4) {
        const long long idx = (long long)q * SEQ + c;
        float o = 0.f;
        if (cvalid && c <= q && q < len) o = __expf(base[idx] - M) * inv;
        base[idx] = o;
    }
}

// ---- fused residual-add + LayerNorm: O = LN(Xa + Xb)*g + be -------------
// one block (256 thr) per row of 768; O may alias Xa or Xb (reads precede
// writes across an intra-block barrier).
__global__ __launch_bounds__(256) void ln_add_kernel(
    const float* __restrict__ Xa, const float* __restrict__ Xb,
    float* __restrict__ O, const float* __restrict__ g,
    const float* __restrict__ be)
{
    const int row = blockIdx.x;
    const long long base = (long long)row * HID;
    const int t = threadIdx.x;
    const float x0 = Xa[base + t]       + Xb[base + t];
    const float x1 = Xa[base + t + 256] + Xb[base + t + 256];
    const float x2 = Xa[base + t + 512] + Xb[base + t + 512];
    __shared__ float r1[4], r2[4];
    float s = x0 + x1 + x2;
    #pragma unroll
    for (int o = 32; o; o >>= 1) s += __shfl_down(s, o, 64);
    if ((t & 63) == 0) r1[t >> 6] = s;
    __syncthreads();
    const float mean = (r1[0] + r1[1] + r1[2] + r1[3]) * (1.f / HID);
    const float d0 = x0 - mean, d1 = x1 - mean, d2 = x2 - mean;
    float v = d0 * d0 + d1 * d1 + d2 * d2;
    #pragma unroll
    for (int o = 32; o; o >>= 1) v += __shfl_down(v, o, 64);
    if ((t & 63) == 0) r2[t >> 6] = v;
    __syncthreads();
    const float var = (r2[0] + r2[1] + r2[2] + r2[3]) * (1.f / HID);
    const float rs = rsqrtf(var + EPSLN);
    O[base + t]       = d0 * rs * g[t]       + be[t];
    O[base + t + 256] = d1 * rs * g[t + 256] + be[t + 256];
    O[base + t + 512] = d2 * rs * g[t + 512] + be[t + 512];
}

// ---- vocab softmax, in place over rows of VOC --------------------------
__global__ __launch_bounds__(256) void softmax_v_kernel(float* __restrict__ out)
{
    const long long base = (long long)blockIdx.x * VOC;
    const int t = threadIdx.x;
    __shared__ float r[4];
    float m = -3.0e38f;
    for (int i = t; i < VOC; i += 256) m = fmaxf(m, out[base + i]);
    #pragma unroll
    for (int o = 32; o; o >>= 1) m = fmaxf(m, __shfl_down(m, o, 64));
    if ((t & 63) == 0) r[t >> 6] = m;
    __syncthreads();
    m = fmaxf(fmaxf(r[0], r[1]), fmaxf(r[2], r[3]));
    __syncthreads();   // r reused below
    float s = 0.f;
    for (int i = t; i < VOC; i += 256) s += __expf(out[base + i] - m);
    #pragma unroll
    for (int o = 32; o; o >>= 1) s += __shfl_down(s, o, 64);
    if ((t & 63) == 0) r[t >> 6] = s;
    __syncthreads();
    const float inv = 1.f / (r[0] + r[1] + r[2] + r[3]);
    for (int i = t; i < VOC; i += 256) out[base + i] = __expf(out[base + i] - m) * inv;
}

// ---- host-side orchestration -------------------------------------------
extern "C" void kernel_launch(void* const* d_in, const int* in_sizes, int n_in,
                              void* d_out, int out_size, void* d_ws, size_t ws_size,
                              hipStream_t stream)
{
    const int*   x    = (const int*)  d_in[0];
    const int*   lens = (const int*)  d_in[1];
    const float* emb  = (const float*)d_in[2];
    const float* Wq   = (const float*)d_in[3];
    const float* bq   = (const float*)d_in[4];
    const float* Wk   = (const float*)d_in[5];
    const float* bk   = (const float*)d_in[6];
    const float* Wv   = (const float*)d_in[7];
    const float* bv   = (const float*)d_in[8];
    const float* W1   = (const float*)d_in[9];
    const float* b1   = (const float*)d_in[10];
    const float* W2   = (const float*)d_in[11];
    const float* b2   = (const float*)d_in[12];
    const float* g1   = (const float*)d_in[13];
    const float* be1  = (const float*)d_in[14];
    const float* g2   = (const float*)d_in[15];
    const float* be2  = (const float*)d_in[16];
    const float* fcw  = (const float*)d_in[17];
    const float* fcb  = (const float*)d_in[18];

    // Scratch plan: everything except zf lives in the (currently unused)
    // d_out region — all of it is dead before the logits GEMM overwrites
    // d_out. 5*NH + B*S*S = 17.8M floats < 40.96M floats of d_out.
    float* out = (float*)d_out;
    float* Qb  = out;                       // also reused as mid1
    float* Kb  = out + NH;                  // also reused as mid
    float* Vb  = out + 2 * NH;
    float* Zb  = out + 3 * NH;
    float* O1  = out + 4 * NH;
    float* ATT = out + 5 * NH;              // B*S*S floats
    float* ZF  = (float*)d_ws;              // NH floats, must survive into logits GEMM

    const float scale = 1.0f / sqrtf((float)HID);
    const long long sQ = (long long)SEQ * HID;  // per-batch stride of [S,H]
    const long long sS = (long long)SEQ * SEQ;  // per-batch stride of [S,S]

    const dim3 blk(256);
    const dim3 gMain(HID / 64, NROWS / 64, 1);       // 12 x 64
    const dim3 gScore(SEQ / 64, SEQ / 64, BATCH);    // 8 x 8 x 8
    const dim3 gAV(HID / 64, SEQ / 64, BATCH);       // 12 x 8 x 8
    const dim3 gSm(BATCH, SEQ / 64, 1);
    const dim3 gLog((VOC + 63) / 64, NROWS / 64, 1); // 157 x 64

    embed_kernel<<<NROWS, blk, 0, stream>>>(x, emb, Zb);

    for (int l = 0; l < LAYERS; ++l) {
        const float* wq = Wq + (long long)l * HID * HID;
        const float* wk = Wk + (long long)l * HID * HID;
        const float* wv = Wv + (long long)l * HID * HID;
        const float* w1 = W1 + (long long)l * HID * HID;
        const float* w2 = W2 + (long long)l * HID * HID;

        gemm_f32<false, false><<<gMain, blk, 0, stream>>>(
            Zb, HID, 0, wq, HID, 0, Qb, HID, 0, NROWS, HID, HID, bq + l * HID, 1.0f);
        gemm_f32<false, false><<<gMain, blk, 0, stream>>>(
            Zb, HID, 0, wk, HID, 0, Kb, HID, 0, NROWS, HID, HID, bk + l * HID, 1.0f);
        gemm_f32<false, false><<<gMain, blk, 0, stream>>>(
            Zb, HID, 0, wv, HID, 0, Vb, HID, 0, NROWS, HID, HID, bv + l * HID, 1.0f);

        // scores[b,q,k] = scale * q-row . k-row   (NT gemm, batched)
        gemm_f32<true, false><<<gScore, blk, 0, stream>>>(
            Qb, HID, sQ, Kb, HID, sQ, ATT, SEQ, sS, SEQ, SEQ, HID, nullptr, scale);

        softmax_q_kernel<<<gSm, blk, 0, stream>>>(ATT, lens);

        // out[b,q,h] = att[b,q,:] @ v[b,:,h]   (NN gemm, batched) -> O1
        gemm_f32<false, false><<<gAV, blk, 0, stream>>>(
            ATT, SEQ, sS, Vb, HID, sQ, O1, HID, sQ, SEQ, HID, SEQ, nullptr, 1.0f);

        // o1 = LN(z + out)
        ln_add_kernel<<<NROWS, blk, 0, stream>>>(Zb, O1, O1, g1 + l * HID, be1 + l * HID);
        // mid1 = relu(o1 @ W1 + b1) -> Qb
        gemm_f32<false, true><<<gMain, blk, 0, stream>>>(
            O1, HID, 0, w1, HID, 0, Qb, HID, 0, NROWS, HID, HID, b1 + l * HID, 1.0f);
        // mid = mid1 @ W2 + b2 -> Kb
        gemm_f32<false, false><<<gMain, blk, 0, stream>>>(
            Qb, HID, 0, w2, HID, 0, Kb, HID, 0, NROWS, HID, HID, b2 + l * HID, 1.0f);
        // z = LN(mid + o1)
        ln_add_kernel<<<NROWS, blk, 0, stream>>>(Kb, O1, Zb, g2 + l * HID, be2 + l * HID);
    }

    // zf = z @ fc_w + fc_b  -> ZF (lives in d_ws: must survive logits GEMM)
    gemm_f32<false, false><<<gMain, blk, 0, stream>>>(
        Zb, HID, 0, fcw, HID, 0, ZF, HID, 0, NROWS, HID, HID, fcb, 1.0f);
    // logits = zf @ emb^T  -> full d_out (overwrites all scratch, now dead)
    gemm_f32<true, false><<<gLog, blk, 0, stream>>>(
        ZF, HID, 0, emb, HID, 0, out, VOC, 0, NROWS, VOC, HID, nullptr, 1.0f);
    // softmax over vocab, in place
    softmax_v_kernel<<<NROWS, blk, 0, stream>>>(out);
}

// Round 2
// 1778.714 us; speedup vs baseline: 3.6410x; 3.6410x over previous
//
#include <hip/hip_runtime.h>
#include <math.h>

typedef unsigned int   u32;
typedef unsigned short u16;
typedef __attribute__((ext_vector_type(8))) short bf16x8;
typedef __attribute__((ext_vector_type(4))) float f32x4;

#define HID   768
#define SEQ   512
#define BATCH 8
#define LAYERS 8
#define VOC   10000
#define NROWS (BATCH*SEQ)             // 4096
#define NH    ((long long)NROWS*HID)  // 3,145,728
#define SS8   ((long long)BATCH*SEQ*SEQ)
#define EPSLN 1e-5f

__device__ __forceinline__ u16 f2bf(float f) {
    u32 u = __builtin_bit_cast(u32, f);
    return (u16)((u + 0x7fffu + ((u >> 16) & 1u)) >> 16);
}

__device__ __forceinline__ void async16(u16* lds, const u16* g) {
    __builtin_amdgcn_global_load_lds(
        (const __attribute__((address_space(1))) u32*)g,
        (__attribute__((address_space(3))) u32*)lds, 16, 0, 0);
}

// ---- embedding + positional encoding (fp32 + bf16 shadow) ---------------
__global__ __launch_bounds__(256) void embed_kernel(
    const int* __restrict__ x, const float* __restrict__ emb,
    float* __restrict__ Z, u16* __restrict__ Zh)
{
    const int row = blockIdx.x;
    const int s   = row & (SEQ - 1);
    const int tok = x[row];
    const long long base  = (long long)row * HID;
    const long long ebase = (long long)tok * HID;
    const float coef = -0.0239852613853544f;   // -2*ln(10000)/768
    #pragma unroll
    for (int j = 0; j < 3; ++j) {
        const int h = threadIdx.x + 256 * j;
        const int i = h >> 1;
        const float ang = (float)s * expf((float)i * coef);
        const float pe  = (h & 1) ? cosf(ang) : sinf(ang);
        const float v = emb[ebase + h] + pe;
        Z[base + h]  = v;
        Zh[base + h] = f2bf(v);
    }
}

// ---- weight transpose+convert: W fp32 [768,768] (K,N) -> bf16 [N,K] -----
// grid (24,24,nmat); dst matrix z at dst + z*768*768
__global__ __launch_bounds__(256) void transp_w(
    const float* __restrict__ s0, const float* __restrict__ s1,
    const float* __restrict__ s2, const float* __restrict__ s3,
    const float* __restrict__ s4, u16* __restrict__ dst)
{
    __shared__ u16 tile[32][34];
    const float* srcs[5] = {s0, s1, s2, s3, s4};
    const float* W = srcs[blockIdx.z];
    u16* D = dst + (long long)blockIdx.z * (768 * 768);
    const int n0 = blockIdx.x * 32, k0 = blockIdx.y * 32;
    const int c = threadIdx.x & 31, r0 = threadIdx.x >> 5;
    #pragma unroll
    for (int p = 0; p < 4; ++p)
        tile[r0 + 8*p][c] = f2bf(W[(long long)(k0 + r0 + 8*p) * 768 + n0 + c]);
    __syncthreads();
    #pragma unroll
    for (int p = 0; p < 4; ++p)
        D[(long long)(n0 + r0 + 8*p) * 768 + k0 + c] = tile[c][r0 + 8*p];
}

// ---- V transpose: QKVh[b,s,1536+h] bf16 -> Vt[b,h,s] bf16 ---------------
// grid (16, 24, 8)
__global__ __launch_bounds__(256) void transp_v(
    const u16* __restrict__ QKV, u16* __restrict__ Vt)
{
    __shared__ u16 tile[32][34];
    const int b = blockIdx.z;
    const int s0 = blockIdx.x * 32, h0 = blockIdx.y * 32;
    const int c = threadIdx.x & 31, r0 = threadIdx.x >> 5;
    #pragma unroll
    for (int p = 0; p < 4; ++p)
        tile[r0 + 8*p][c] =
            QKV[(long long)(b*SEQ + s0 + r0 + 8*p) * 2304 + 1536 + h0 + c];
    __syncthreads();
    #pragma unroll
    for (int p = 0; p < 4; ++p)
        Vt[((long long)b*HID + h0 + r0 + 8*p) * SEQ + s0 + c] = tile[c][r0 + 8*p];
}

// ---- pack qkv biases: [L][3*768] ---------------------------------------
__global__ void pack_bias_all(const float* __restrict__ bq,
                              const float* __restrict__ bk,
                              const float* __restrict__ bv,
                              float* __restrict__ dst)
{
    const int part = blockIdx.x, l = blockIdx.y, h = threadIdx.x;
    const float* src = part == 0 ? bq : (part == 1 ? bk : bv);
    dst[((long long)l*3 + part) * 768 + h] = src[(long long)l*768 + h];
}

// ---- MFMA GEMM: C = alpha*(A @ B^T) + bias, opt relu --------------------
// A: bf16 [M,K] k-contig. B: bf16 [N,K] k-contig (or fp32 [N,K] if CONV_B,
// converted during staging). C: fp32 or bf16 [M,N]. BM=128 fixed.
// grid (N/BN ceil, M/128, batch). 256 threads = 4 waves (2x2), wave tile
// 64 x BN/2, frags 4 x BN/32 of 16x16x32.
template<int BN, bool CONV_B, bool RELU, bool OUT_BF16>
__global__ __launch_bounds__(256) void gemm_mfma(
    const u16* __restrict__ A, int lda, long long sA,
    const void* __restrict__ Bp, int ldb, long long sB,
    void* __restrict__ Cp, int ldc, long long sC,
    int N, int K, const float* __restrict__ bias, float alpha)
{
    constexpr int NI = BN / 32;
    __shared__ u16 As[128 * 32];
    __shared__ u16 Bs[BN * 32];
    const int bz = blockIdx.z;
    const int m0 = blockIdx.y * 128;
    const int n0 = blockIdx.x * BN;
    const int t = threadIdx.x, w = t >> 6, l = t & 63;
    const int lrow = l >> 2, lk8 = (l & 3) * 8;
    const int wm = (w >> 1) * 64, wn = (w & 1) * (BN / 2);
    A += sA * bz;
    const u16*   Bh = (const u16*)Bp + sB * bz;
    const float* Bf = (const float*)Bp + sB * bz;

    const f32x4 fz = {0.f, 0.f, 0.f, 0.f};
    f32x4 acc[4][NI];
    #pragma unroll
    for (int mi = 0; mi < 4; ++mi)
        #pragma unroll
        for (int ni = 0; ni < NI; ++ni) acc[mi][ni] = fz;

    for (int k0 = 0; k0 < K; k0 += 32) {
        // stage A (8 KB): 2 x 1KB per wave via global_load_lds
        #pragma unroll
        for (int r = 0; r < 2; ++r) {
            const int seg = w * 2 + r;
            async16(&As[seg * 512],
                    A + (long long)(m0 + seg*16 + lrow) * lda + (k0 + lk8));
        }
        if constexpr (!CONV_B) {
            #pragma unroll
            for (int r = 0; r < BN / 64; ++r) {
                const int seg = w + r * 4;
                int row = n0 + seg*16 + lrow;
                row = row < N ? row : N - 1;
                async16(&Bs[seg * 512], Bh + (long long)row * ldb + (k0 + lk8));
            }
        } else {
            #pragma unroll
            for (int r = 0; r < BN / 64; ++r) {
                const int flat = r * 2048 + t * 8;
                int row = n0 + (flat >> 5);
                row = row < N ? row : N - 1;
                const float* g = Bf + (long long)row * ldb + (k0 + (flat & 31));
                const float4 v0 = *(const float4*)g;
                const float4 v1 = *(const float4*)(g + 4);
                bf16x8 hv;
                hv[0]=(short)f2bf(v0.x); hv[1]=(short)f2bf(v0.y);
                hv[2]=(short)f2bf(v0.z); hv[3]=(short)f2bf(v0.w);
                hv[4]=(short)f2bf(v1.x); hv[5]=(short)f2bf(v1.y);
                hv[6]=(short)f2bf(v1.z); hv[7]=(short)f2bf(v1.w);
                *(bf16x8*)&Bs[flat] = hv;
            }
        }
        __syncthreads();
        const int fr = l & 15, fk = (l >> 4) * 8;
        bf16x8 af[4], bfr[NI];
        #pragma unroll
        for (int mi = 0; mi < 4; ++mi)
            af[mi] = *(const bf16x8*)&As[(wm + mi*16 + fr) * 32 + fk];
        #pragma unroll
        for (int ni = 0; ni < NI; ++ni)
            bfr[ni] = *(const bf16x8*)&Bs[(wn + ni*16 + fr) * 32 + fk];
        #pragma unroll
        for (int mi = 0; mi < 4; ++mi)
            #pragma unroll
            for (int ni = 0; ni < NI; ++ni)
                acc[mi][ni] = __builtin_amdgcn_mfma_f32_16x16x32_bf16(
                    af[mi], bfr[ni], acc[mi][ni], 0, 0, 0);
        __syncthreads();
    }

    float* Cf = (float*)Cp + sC * bz;
    u16*   Ch = (u16*)Cp + sC * bz;
    const int fr = l & 15, fq = l >> 4;
    #pragma unroll
    for (int ni = 0; ni < NI; ++ni) {
        const int col = n0 + wn + ni*16 + fr;
        const bool ok = col < N;
        const float bv = (bias && ok) ? bias[col] : 0.f;
        #pragma unroll
        for (int mi = 0; mi < 4; ++mi) {
            const int row0 = m0 + wm + mi*16 + fq*4;
            #pragma unroll
            for (int v = 0; v < 4; ++v) {
                float val = alpha * acc[mi][ni][v] + bv;
                if (RELU) val = fmaxf(val, 0.f);
                if (ok) {
                    if (OUT_BF16) Ch[(long long)(row0 + v) * ldc + col] = f2bf(val);
                    else          Cf[(long long)(row0 + v) * ldc + col] = val;
                }
            }
        }
    }
}

// ---- masked softmax over the QUERY axis (dim=1): fp32 in, bf16 out ------
__global__ __launch_bounds__(256) void softmax_q_kernel(
    const float* __restrict__ sc, u16* __restrict__ att,
    const int* __restrict__ lengths)
{
    const int b  = blockIdx.x;
    const int k0 = blockIdx.y * 64;
    const int tx = threadIdx.x & 63;
    const int ty = threadIdx.x >> 6;
    const int c  = k0 + tx;
    const int len = lengths[b];
    const float* base = sc  + (long long)b * SEQ * SEQ;
    u16*         obase = att + (long long)b * SEQ * SEQ;
    const bool cvalid = (c < len);

    float m = -3.0e38f, ssum = 0.f;
    for (int q = ty; q < SEQ; q += 4) {
        if (cvalid && c <= q && q < len) {
            const float xv = base[(long long)q * SEQ + c];
            if (xv > m) { ssum = ssum * __expf(m - xv) + 1.f; m = xv; }
            else        { ssum += __expf(xv - m); }
        }
    }
    __shared__ float ms[4][64], ss[4][64];
    ms[ty][tx] = m; ss[ty][tx] = ssum;
    __syncthreads();
    if (ty == 0) {
        float M = ms[0][tx];
        #pragma unroll
        for (int r = 1; r < 4; ++r) M = fmaxf(M, ms[r][tx]);
        float Sx = 0.f;
        #pragma unroll
        for (int r = 0; r < 4; ++r) Sx += ss[r][tx] * __expf(ms[r][tx] - M);
        ms[0][tx] = M; ss[0][tx] = Sx;
    }
    __syncthreads();
    const float M   = ms[0][tx];
    const float den = ss[0][tx];
    const float inv = (den > 0.f) ? 1.f / den : 0.f;
    for (int q = ty; q < SEQ; q += 4) {
        const long long idx = (long long)q * SEQ + c;
        float o = 0.f;
        if (cvalid && c <= q && q < len) o = __expf(base[idx] - M) * inv;
        obase[idx] = f2bf(o);
    }
}

// ---- fused residual-add + LayerNorm, fp32 + bf16 outputs ---------------
__global__ __launch_bounds__(256) void ln_add_kernel(
    const float* __restrict__ Xa, const float* __restrict__ Xb,
    float* __restrict__ O, u16* __restrict__ Oh,
    const float* __restrict__ g, const float* __restrict__ be)
{
    const int row = blockIdx.x;
    const long long base = (long long)row * HID;
    const int t = threadIdx.x;
    const float x0 = Xa[base + t]       + Xb[base + t];
    const float x1 = Xa[base + t + 256] + Xb[base + t + 256];
    const float x2 = Xa[base + t + 512] + Xb[base + t + 512];
    __shared__ float r1[4], r2[4];
    float s = x0 + x1 + x2;
    #pragma unroll
    for (int o = 32; o; o >>= 1) s += __shfl_down(s, o, 64);
    if ((t & 63) == 0) r1[t >> 6] = s;
    __syncthreads();
    const float mean = (r1[0] + r1[1] + r1[2] + r1[3]) * (1.f / HID);
    const float d0 = x0 - mean, d1 = x1 - mean, d2 = x2 - mean;
    float v = d0*d0 + d1*d1 + d2*d2;
    #pragma unroll
    for (int o = 32; o; o >>= 1) v += __shfl_down(v, o, 64);
    if ((t & 63) == 0) r2[t >> 6] = v;
    __syncthreads();
    const float var = (r2[0] + r2[1] + r2[2] + r2[3]) * (1.f / HID);
    const float rs = rsqrtf(var + EPSLN);
    const float y0 = d0 * rs * g[t]       + be[t];
    const float y1 = d1 * rs * g[t + 256] + be[t + 256];
    const float y2 = d2 * rs * g[t + 512] + be[t + 512];
    O[base + t]        = y0;  Oh[base + t]       = f2bf(y0);
    O[base + t + 256]  = y1;  Oh[base + t + 256] = f2bf(y1);
    O[base + t + 512]  = y2;  Oh[base + t + 512] = f2bf(y2);
}

// ---- vocab softmax, in place, 2 passes, float4 -------------------------
__global__ __launch_bounds__(256) void softmax_v_kernel(float* __restrict__ out)
{
    float4* o4 = (float4*)(out + (long long)blockIdx.x * VOC);
    const int t = threadIdx.x;
    float m = -3.0e38f, s = 0.f;
    for (int i = t; i < VOC/4; i += 256) {
        const float4 v = o4[i];
        #pragma unroll
        for (int j = 0; j < 4; ++j) {
            const float xv = j==0?v.x:(j==1?v.y:(j==2?v.z:v.w));
            const float d = xv - m;
            if (d > 0.f) { s = s * __expf(-d) + 1.f; m = xv; }
            else         { s += __expf(d); }
        }
    }
    #pragma unroll
    for (int o = 32; o; o >>= 1) {
        const float om = __shfl_down(m, o, 64), os = __shfl_down(s, o, 64);
        const float M = fmaxf(m, om);
        s = s * __expf(m - M) + os * __expf(om - M);
        m = M;
    }
    __shared__ float rm[4], rs_[4];
    if ((t & 63) == 0) { rm[t >> 6] = m; rs_[t >> 6] = s; }
    __syncthreads();
    const float M = fmaxf(fmaxf(rm[0], rm[1]), fmaxf(rm[2], rm[3]));
    const float S = rs_[0]*__expf(rm[0]-M) + rs_[1]*__expf(rm[1]-M)
                  + rs_[2]*__expf(rm[2]-M) + rs_[3]*__expf(rm[3]-M);
    const float inv = 1.f / S;
    for (int i = t; i < VOC/4; i += 256) {
        float4 v = o4[i];
        v.x = __expf(v.x - M) * inv;
        v.y = __expf(v.y - M) * inv;
        v.z = __expf(v.z - M) * inv;
        v.w = __expf(v.w - M) * inv;
        o4[i] = v;
    }
}

// ---- host-side orchestration -------------------------------------------
extern "C" void kernel_launch(void* const* d_in, const int* in_sizes, int n_in,
                              void* d_out, int out_size, void* d_ws, size_t ws_size,
                              hipStream_t stream)
{
    const int*   x    = (const int*)  d_in[0];
    const int*   lens = (const int*)  d_in[1];
    const float* emb  = (const float*)d_in[2];
    const float* Wq   = (const float*)d_in[3];
    const float* bq   = (const float*)d_in[4];
    const float* Wk   = (const float*)d_in[5];
    const float* bk   = (const float*)d_in[6];
    const float* Wv   = (const float*)d_in[7];
    const float* bv   = (const float*)d_in[8];
    const float* W1   = (const float*)d_in[9];
    const float* b1   = (const float*)d_in[10];
    const float* W2   = (const float*)d_in[11];
    const float* b2   = (const float*)d_in[12];
    const float* g1   = (const float*)d_in[13];
    const float* be1  = (const float*)d_in[14];
    const float* g2   = (const float*)d_in[15];
    const float* be2  = (const float*)d_in[16];
    const float* fcw  = (const float*)d_in[17];
    const float* fcb  = (const float*)d_in[18];

    // Scratch in dead d_out region (all dead before logits GEMM writes out).
    float* out = (float*)d_out;
    long long o = 0;
    float* Zb     = out + o; o += NH;
    float* O1f    = out + o; o += NH;
    float* M2f    = out + o; o += NH;
    float* SCORES = out + o; o += SS8;
    u16* ub = (u16*)(out + o);
    u16* Zbh  = ub; ub += NH;
    u16* QKVh = ub; ub += (long long)NROWS * 2304;
    u16* ATTB = ub; ub += SS8;
    u16* Vt   = ub; ub += (long long)BATCH * HID * SEQ;
    u16* O1h  = ub; ub += NH;
    u16* M1h  = ub; ub += NH;
    u16* WBt  = ub; ub += (long long)3840 * HID;   // [qkv 2304 | W1t 768 | W2t 768] x 768
    float* BQKV = (float*)ub;                       // [L][2304]
    u16* ZFh = (u16*)d_ws;                          // bf16 zf, survives logits GEMM

    const float scale = 1.0f / sqrtf((float)HID);
    const long long HH = (long long)HID * HID;
    const dim3 blk(256);

    embed_kernel<<<NROWS, blk, 0, stream>>>(x, emb, Zb, Zbh);
    pack_bias_all<<<dim3(3, LAYERS), dim3(768), 0, stream>>>(bq, bk, bv, BQKV);

    for (int l = 0; l < LAYERS; ++l) {
        transp_w<<<dim3(24, 24, 5), blk, 0, stream>>>(
            Wq + l*HH, Wk + l*HH, Wv + l*HH, W1 + l*HH, W2 + l*HH, WBt);

        // qkv = z @ [Wq|Wk|Wv] + b  -> bf16 [4096,2304]
        gemm_mfma<128, false, false, true><<<dim3(18, 32, 1), blk, 0, stream>>>(
            Zbh, HID, 0, WBt, HID, 0, QKVh, 2304, 0,
            2304, HID, BQKV + (long long)l*2304, 1.0f);

        // scores = scale * Q @ K^T -> fp32 [b,512,512]
        gemm_mfma<64, false, false, false><<<dim3(8, 4, BATCH), blk, 0, stream>>>(
            QKVh, 2304, (long long)SEQ*2304,
            QKVh + 768, 2304, (long long)SEQ*2304,
            SCORES, SEQ, (long long)SEQ*SEQ,
            SEQ, HID, nullptr, scale);

        softmax_q_kernel<<<dim3(BATCH, SEQ/64), blk, 0, stream>>>(SCORES, ATTB, lens);
        transp_v<<<dim3(16, 24, BATCH), blk, 0, stream>>>(QKVh, Vt);

        // attnout = att @ V -> fp32 [b,512,768]
        gemm_mfma<64, false, false, false><<<dim3(12, 4, BATCH), blk, 0, stream>>>(
            ATTB, SEQ, (long long)SEQ*SEQ,
            Vt, SEQ, (long long)HID*SEQ,
            O1f, HID, (long long)SEQ*HID,
            HID, SEQ, nullptr, 1.0f);

        ln_add_kernel<<<NROWS, blk, 0, stream>>>(Zb, O1f, O1f, O1h,
                                                 g1 + l*HID, be1 + l*HID);
        // mid1 = relu(o1 @ W1 + b1) -> bf16
        gemm_mfma<64, false, true, true><<<dim3(12, 32, 1), blk, 0, stream>>>(
            O1h, HID, 0, WBt + (long long)2304*HID, HID, 0, M1h, HID, 0,
            HID, HID, b1 + l*HID, 1.0f);
        // mid = mid1 @ W2 + b2 -> fp32
        gemm_mfma<64, false, false, false><<<dim3(12, 32, 1), blk, 0, stream>>>(
            M1h, HID, 0, WBt + (long long)3072*HID, HID, 0, M2f, HID, 0,
            HID, HID, b2 + l*HID, 1.0f);
        ln_add_kernel<<<NROWS, blk, 0, stream>>>(M2f, O1f, Zb, Zbh,
                                                 g2 + l*HID, be2 + l*HID);
    }

    // fc: zf = z @ fc_w + fc_b -> bf16 in d_ws
    transp_w<<<dim3(24, 24, 1), blk, 0, stream>>>(fcw, fcw, fcw, fcw, fcw, WBt);
    gemm_mfma<64, false, false, true><<<dim3(12, 32, 1), blk, 0, stream>>>(
        Zbh, HID, 0, WBt, HID, 0, ZFh, HID, 0, HID, HID, fcb, 1.0f);

    // logits = zf @ emb^T -> fp32 full d_out (B staged fp32->bf16 in-flight)
    gemm_mfma<128, true, false, false><<<dim3((VOC + 127)/128, 32, 1), blk, 0, stream>>>(
        ZFh, HID, 0, emb, HID, 0, out, VOC, 0, VOC, HID, nullptr, 1.0f);

    softmax_v_kernel<<<NROWS, blk, 0, stream>>>(out);
}

// Round 3
// 1639.927 us; speedup vs baseline: 3.9491x; 1.0846x over previous
//
#include <hip/hip_runtime.h>
#include <math.h>

typedef unsigned int   u32;
typedef unsigned short u16;
typedef __attribute__((ext_vector_type(8))) short bf16x8;
typedef __attribute__((ext_vector_type(4))) float f32x4;
typedef __attribute__((ext_vector_type(4))) unsigned short u16x4;

#define HID   768
#define SEQ   512
#define BATCH 8
#define LAYERS 8
#define VOC   10000
#define NROWS (BATCH*SEQ)             // 4096
#define NH    ((long long)NROWS*HID)  // 3,145,728
#define SS8   ((long long)BATCH*SEQ*SEQ)
#define EPSLN 1e-5f
#define WSZ   ((long long)HID*HID)    // 589824

__device__ __forceinline__ u16 f2bf(float f) {
    u32 u = __builtin_bit_cast(u32, f);
    return (u16)((u + 0x7fffu + ((u >> 16) & 1u)) >> 16);
}

__device__ __forceinline__ void async16(u16* lds, const u16* g) {
    __builtin_amdgcn_global_load_lds(
        (const __attribute__((address_space(1))) u32*)g,
        (__attribute__((address_space(3))) u32*)lds, 16, 0, 0);
}

// ---- embedding + positional encoding (fp32 + bf16 shadow) ---------------
__global__ __launch_bounds__(256) void embed_kernel(
    const int* __restrict__ x, const float* __restrict__ emb,
    float* __restrict__ Z, u16* __restrict__ Zh)
{
    const int row = blockIdx.x;
    const int s   = row & (SEQ - 1);
    const int tok = x[row];
    const long long base  = (long long)row * HID;
    const long long ebase = (long long)tok * HID;
    const float coef = -0.0239852613853544f;   // -2*ln(10000)/768
    #pragma unroll
    for (int j = 0; j < 3; ++j) {
        const int h = threadIdx.x + 256 * j;
        const int i = h >> 1;
        const float ang = (float)s * expf((float)i * coef);
        const float pe  = (h & 1) ? cosf(ang) : sinf(ang);
        const float v = emb[ebase + h] + pe;
        Z[base + h]  = v;
        Zh[base + h] = f2bf(v);
    }
}

// ---- emb fp32 -> bf16, vectorized --------------------------------------
__global__ __launch_bounds__(256) void convert_emb(
    const float* __restrict__ e, u16* __restrict__ eh)
{
    const long long i = ((long long)blockIdx.x * 256 + threadIdx.x) * 4;
    const float4 v = *(const float4*)&e[i];
    u16x4 p;
    p[0] = f2bf(v.x); p[1] = f2bf(v.y); p[2] = f2bf(v.z); p[3] = f2bf(v.w);
    *(u16x4*)&eh[i] = p;
}

// ---- all-weights transpose+convert: fp32 [K,N] -> bf16 [N,K] ------------
// z<40: layer z/5, mat z%5 (Wq,Wk,Wv,W1,W2); z==40: fc_w. grid (24,24,41)
__global__ __launch_bounds__(256) void transp_all(
    const float* __restrict__ Wq, const float* __restrict__ Wk,
    const float* __restrict__ Wv, const float* __restrict__ W1,
    const float* __restrict__ W2, const float* __restrict__ fcw,
    u16* __restrict__ WT)
{
    __shared__ u16 tile[32][34];
    const int z = blockIdx.z;
    const float* src;
    long long doff;
    if (z < 40) {
        const int lyr = z / 5, idx = z % 5;
        const float* bases[5] = {Wq, Wk, Wv, W1, W2};
        src  = bases[idx] + (long long)lyr * WSZ;
        doff = ((long long)lyr * 5 + idx) * WSZ;
    } else {
        src = fcw; doff = 40LL * WSZ;
    }
    u16* D = WT + doff;
    const int n0 = blockIdx.x * 32, k0 = blockIdx.y * 32;
    const int c = threadIdx.x & 31, r0 = threadIdx.x >> 5;
    #pragma unroll
    for (int p = 0; p < 4; ++p)
        tile[r0 + 8*p][c] = f2bf(src[(long long)(k0 + r0 + 8*p) * HID + n0 + c]);
    __syncthreads();
    #pragma unroll
    for (int p = 0; p < 4; ++p)
        D[(long long)(n0 + r0 + 8*p) * HID + k0 + c] = tile[c][r0 + 8*p];
}

// ---- pack qkv biases: [L][3*768] ---------------------------------------
__global__ void pack_bias_all(const float* __restrict__ bq,
                              const float* __restrict__ bk,
                              const float* __restrict__ bv,
                              float* __restrict__ dst)
{
    const int part = blockIdx.x, l = blockIdx.y, h = threadIdx.x;
    const float* src = part == 0 ? bq : (part == 1 ? bk : bv);
    dst[((long long)l*3 + part) * HID + h] = src[(long long)l*HID + h];
}

// ---- MFMA GEMM, 2-phase double-buffered (T3-minimal recipe) -------------
// A: bf16 [M,K] k-contig. B: bf16 [N,K] k-contig. C: fp32 or bf16 [M,N].
// BM=128. 256 thr = 4 waves (2x2). XISM: blockIdx.x indexes M (B-tile reuse
// between consecutive blocks). VSPLIT: cols<1536 -> Ch (ldc), cols>=1536
// written TRANSPOSED to vt[b][col-1536][s] (V for the PV gemm).
template<int BN, bool RELU, bool OUT_BF16, bool XISM, bool VSPLIT>
__global__ __launch_bounds__(256) void gemm_mfma(
    const u16* __restrict__ A, int lda, long long sA,
    const u16* __restrict__ B, int ldb, long long sB,
    void* __restrict__ Cp, int ldc, long long sC,
    int N, int K, const float* __restrict__ bias, float alpha,
    u16* __restrict__ vt)
{
    constexpr int NI = BN / 32;
    __shared__ u16 As[2][128 * 32];
    __shared__ u16 Bs[2][BN * 32];
    const int bz = blockIdx.z;
    const int m0 = (XISM ? blockIdx.x : blockIdx.y) * 128;
    const int n0 = (XISM ? blockIdx.y : blockIdx.x) * BN;
    const int t = threadIdx.x, w = t >> 6, l = t & 63;
    const int lrow = l >> 2, lk8 = (l & 3) * 8;
    const int wm = (w >> 1) * 64, wn = (w & 1) * (BN / 2);
    A += sA * bz; B += sB * bz;

    f32x4 acc[4][NI];
    #pragma unroll
    for (int mi = 0; mi < 4; ++mi)
        #pragma unroll
        for (int ni = 0; ni < NI; ++ni) acc[mi][ni] = (f32x4){0.f,0.f,0.f,0.f};

    auto stage = [&](int buf, int k0) {
        #pragma unroll
        for (int r = 0; r < 2; ++r) {
            const int seg = w * 2 + r;
            async16(&As[buf][seg * 512],
                    A + (long long)(m0 + seg*16 + lrow) * lda + (k0 + lk8));
        }
        #pragma unroll
        for (int r = 0; r < BN / 64; ++r) {
            const int seg = w + r * 4;
            int row = n0 + seg*16 + lrow;
            row = row < N ? row : N - 1;
            async16(&Bs[buf][seg * 512], B + (long long)row * ldb + (k0 + lk8));
        }
    };
    auto compute = [&](int cur) {
        const int fr = l & 15, fk = (l >> 4) * 8;
        bf16x8 af[4], bfr[NI];
        #pragma unroll
        for (int mi = 0; mi < 4; ++mi)
            af[mi] = *(const bf16x8*)&As[cur][(wm + mi*16 + fr) * 32 + fk];
        #pragma unroll
        for (int ni = 0; ni < NI; ++ni)
            bfr[ni] = *(const bf16x8*)&Bs[cur][(wn + ni*16 + fr) * 32 + fk];
        #pragma unroll
        for (int mi = 0; mi < 4; ++mi)
            #pragma unroll
            for (int ni = 0; ni < NI; ++ni)
                acc[mi][ni] = __builtin_amdgcn_mfma_f32_16x16x32_bf16(
                    af[mi], bfr[ni], acc[mi][ni], 0, 0, 0);
    };

    const int NS = K >> 5;
    stage(0, 0);
    asm volatile("s_waitcnt vmcnt(0)" ::: "memory");
    __builtin_amdgcn_s_barrier();
    int cur = 0;
    for (int tt = 0; tt < NS - 1; ++tt) {
        stage(cur ^ 1, (tt + 1) << 5);     // next tile in flight under compute
        compute(cur);
        asm volatile("s_waitcnt vmcnt(0)" ::: "memory");
        __builtin_amdgcn_s_barrier();
        cur ^= 1;
    }
    compute(cur);

    float* Cf = (float*)Cp + sC * bz;
    u16*   Ch = (u16*)Cp + sC * bz;
    const int fr = l & 15, fq = l >> 4;
    #pragma unroll
    for (int ni = 0; ni < NI; ++ni) {
        const int col = n0 + wn + ni*16 + fr;
        const bool ok = col < N;
        const float bv = (bias && ok) ? bias[col] : 0.f;
        #pragma unroll
        for (int mi = 0; mi < 4; ++mi) {
            const int row0 = m0 + wm + mi*16 + fq*4;
            if constexpr (VSPLIT) {
                if (col < 1536) {
                    #pragma unroll
                    for (int v = 0; v < 4; ++v)
                        Ch[(long long)(row0 + v) * ldc + col] =
                            f2bf(alpha * acc[mi][ni][v] + bv);
                } else {
                    const int b9 = row0 >> 9, s9 = row0 & 511;
                    u16x4 pk;
                    #pragma unroll
                    for (int v = 0; v < 4; ++v)
                        pk[v] = f2bf(alpha * acc[mi][ni][v] + bv);
                    *(u16x4*)&vt[((long long)b9 * HID + (col - 1536)) * SEQ + s9] = pk;
                }
            } else {
                #pragma unroll
                for (int v = 0; v < 4; ++v) {
                    float val = alpha * acc[mi][ni][v] + bv;
                    if (RELU) val = fmaxf(val, 0.f);
                    if (ok) {
                        if (OUT_BF16) Ch[(long long)(row0 + v) * ldc + col] = f2bf(val);
                        else          Cf[(long long)(row0 + v) * ldc + col] = val;
                    }
                }
            }
        }
    }
}

// ---- fallback logits GEMM (fp32 B converted in-flight), grid (32m,79n) --
__global__ __launch_bounds__(256) void gemm_conv(
    const u16* __restrict__ A, const float* __restrict__ Bf,
    float* __restrict__ C)
{
    __shared__ u16 As[128 * 32];
    __shared__ u16 Bs[128 * 32];
    const int m0 = blockIdx.x * 128;
    const int n0 = blockIdx.y * 128;
    const int t = threadIdx.x, w = t >> 6, l = t & 63;
    const int lrow = l >> 2, lk8 = (l & 3) * 8;
    const int wm = (w >> 1) * 64, wn = (w & 1) * 64;
    f32x4 acc[4][4];
    #pragma unroll
    for (int mi = 0; mi < 4; ++mi)
        #pragma unroll
        for (int ni = 0; ni < 4; ++ni) acc[mi][ni] = (f32x4){0.f,0.f,0.f,0.f};

    for (int k0 = 0; k0 < HID; k0 += 32) {
        #pragma unroll
        for (int r = 0; r < 2; ++r) {
            const int seg = w * 2 + r;
            async16(&As[seg * 512],
                    A + (long long)(m0 + seg*16 + lrow) * HID + (k0 + lk8));
        }
        #pragma unroll
        for (int r = 0; r < 2; ++r) {
            const int flat = r * 2048 + t * 8;
            int row = n0 + (flat >> 5);
            row = row < VOC ? row : VOC - 1;
            const float* g = Bf + (long long)row * HID + (k0 + (flat & 31));
            const float4 v0 = *(const float4*)g;
            const float4 v1 = *(const float4*)(g + 4);
            bf16x8 hv;
            hv[0]=(short)f2bf(v0.x); hv[1]=(short)f2bf(v0.y);
            hv[2]=(short)f2bf(v0.z); hv[3]=(short)f2bf(v0.w);
            hv[4]=(short)f2bf(v1.x); hv[5]=(short)f2bf(v1.y);
            hv[6]=(short)f2bf(v1.z); hv[7]=(short)f2bf(v1.w);
            *(bf16x8*)&Bs[flat] = hv;
        }
        __syncthreads();
        const int fr = l & 15, fk = (l >> 4) * 8;
        bf16x8 af[4], bfr[4];
        #pragma unroll
        for (int mi = 0; mi < 4; ++mi)
            af[mi] = *(const bf16x8*)&As[(wm + mi*16 + fr) * 32 + fk];
        #pragma unroll
        for (int ni = 0; ni < 4; ++ni)
            bfr[ni] = *(const bf16x8*)&Bs[(wn + ni*16 + fr) * 32 + fk];
        #pragma unroll
        for (int mi = 0; mi < 4; ++mi)
            #pragma unroll
            for (int ni = 0; ni < 4; ++ni)
                acc[mi][ni] = __builtin_amdgcn_mfma_f32_16x16x32_bf16(
                    af[mi], bfr[ni], acc[mi][ni], 0, 0, 0);
        __syncthreads();
    }
    const int fr = l & 15, fq = l >> 4;
    #pragma unroll
    for (int ni = 0; ni < 4; ++ni) {
        const int col = n0 + wn + ni*16 + fr;
        if (col >= VOC) continue;
        #pragma unroll
        for (int mi = 0; mi < 4; ++mi) {
            const int row0 = m0 + wm + mi*16 + fq*4;
            #pragma unroll
            for (int v = 0; v < 4; ++v)
                C[(long long)(row0 + v) * VOC + col] = acc[mi][ni][v];
        }
    }
}

// ---- masked softmax over the QUERY axis (dim=1): fp32 in, bf16 out ------
__global__ __launch_bounds__(256) void softmax_q_kernel(
    const float* __restrict__ sc, u16* __restrict__ att,
    const int* __restrict__ lengths)
{
    const int b  = blockIdx.x;
    const int k0 = blockIdx.y * 64;
    const int tx = threadIdx.x & 63;
    const int ty = threadIdx.x >> 6;
    const int c  = k0 + tx;
    const int len = lengths[b];
    const float* base  = sc  + (long long)b * SEQ * SEQ;
    u16*         obase = att + (long long)b * SEQ * SEQ;
    const bool cvalid = (c < len);

    float m = -3.0e38f, ssum = 0.f;
    for (int q = ty; q < SEQ; q += 4) {
        if (cvalid && c <= q && q < len) {
            const float xv = base[(long long)q * SEQ + c];
            if (xv > m) { ssum = ssum * __expf(m - xv) + 1.f; m = xv; }
            else        { ssum += __expf(xv - m); }
        }
    }
    __shared__ float ms[4][64], ss[4][64];
    ms[ty][tx] = m; ss[ty][tx] = ssum;
    __syncthreads();
    if (ty == 0) {
        float M = ms[0][tx];
        #pragma unroll
        for (int r = 1; r < 4; ++r) M = fmaxf(M, ms[r][tx]);
        float Sx = 0.f;
        #pragma unroll
        for (int r = 0; r < 4; ++r) Sx += ss[r][tx] * __expf(ms[r][tx] - M);
        ms[0][tx] = M; ss[0][tx] = Sx;
    }
    __syncthreads();
    const float M   = ms[0][tx];
    const float den = ss[0][tx];
    const float inv = (den > 0.f) ? 1.f / den : 0.f;
    for (int q = ty; q < SEQ; q += 4) {
        const long long idx = (long long)q * SEQ + c;
        float o = 0.f;
        if (cvalid && c <= q && q < len) o = __expf(base[idx] - M) * inv;
        obase[idx] = f2bf(o);
    }
}

// ---- fused residual-add + LayerNorm, fp32 + bf16 outputs ---------------
__global__ __launch_bounds__(256) void ln_add_kernel(
    const float* __restrict__ Xa, const float* __restrict__ Xb,
    float* __restrict__ O, u16* __restrict__ Oh,
    const float* __restrict__ g, const float* __restrict__ be)
{
    const int row = blockIdx.x;
    const long long base = (long long)row * HID;
    const int t = threadIdx.x;
    const float x0 = Xa[base + t]       + Xb[base + t];
    const float x1 = Xa[base + t + 256] + Xb[base + t + 256];
    const float x2 = Xa[base + t + 512] + Xb[base + t + 512];
    __shared__ float r1[4], r2[4];
    float s = x0 + x1 + x2;
    #pragma unroll
    for (int o = 32; o; o >>= 1) s += __shfl_down(s, o, 64);
    if ((t & 63) == 0) r1[t >> 6] = s;
    __syncthreads();
    const float mean = (r1[0] + r1[1] + r1[2] + r1[3]) * (1.f / HID);
    const float d0 = x0 - mean, d1 = x1 - mean, d2 = x2 - mean;
    float v = d0*d0 + d1*d1 + d2*d2;
    #pragma unroll
    for (int o = 32; o; o >>= 1) v += __shfl_down(v, o, 64);
    if ((t & 63) == 0) r2[t >> 6] = v;
    __syncthreads();
    const float var = (r2[0] + r2[1] + r2[2] + r2[3]) * (1.f / HID);
    const float rs = rsqrtf(var + EPSLN);
    const float y0 = d0 * rs * g[t]       + be[t];
    const float y1 = d1 * rs * g[t + 256] + be[t + 256];
    const float y2 = d2 * rs * g[t + 512] + be[t + 512];
    O[base + t]        = y0;  Oh[base + t]       = f2bf(y0);
    O[base + t + 256]  = y1;  Oh[base + t + 256] = f2bf(y1);
    O[base + t + 512]  = y2;  Oh[base + t + 512] = f2bf(y2);
}

// ---- vocab softmax, in place, 2 passes, float4 -------------------------
__global__ __launch_bounds__(256) void softmax_v_kernel(float* __restrict__ out)
{
    float4* o4 = (float4*)(out + (long long)blockIdx.x * VOC);
    const int t = threadIdx.x;
    float m = -3.0e38f, s = 0.f;
    for (int i = t; i < VOC/4; i += 256) {
        const float4 v = o4[i];
        #pragma unroll
        for (int j = 0; j < 4; ++j) {
            const float xv = j==0?v.x:(j==1?v.y:(j==2?v.z:v.w));
            const float d = xv - m;
            if (d > 0.f) { s = s * __expf(-d) + 1.f; m = xv; }
            else         { s += __expf(d); }
        }
    }
    #pragma unroll
    for (int o = 32; o; o >>= 1) {
        const float om = __shfl_down(m, o, 64), os = __shfl_down(s, o, 64);
        const float M = fmaxf(m, om);
        s = s * __expf(m - M) + os * __expf(om - M);
        m = M;
    }
    __shared__ float rm[4], rs_[4];
    if ((t & 63) == 0) { rm[t >> 6] = m; rs_[t >> 6] = s; }
    __syncthreads();
    const float M = fmaxf(fmaxf(rm[0], rm[1]), fmaxf(rm[2], rm[3]));
    const float S = rs_[0]*__expf(rm[0]-M) + rs_[1]*__expf(rm[1]-M)
                  + rs_[2]*__expf(rm[2]-M) + rs_[3]*__expf(rm[3]-M);
    const float inv = 1.f / S;
    for (int i = t; i < VOC/4; i += 256) {
        float4 v = o4[i];
        v.x = __expf(v.x - M) * inv;
        v.y = __expf(v.y - M) * inv;
        v.z = __expf(v.z - M) * inv;
        v.w = __expf(v.w - M) * inv;
        o4[i] = v;
    }
}

// ---- host-side orchestration -------------------------------------------
extern "C" void kernel_launch(void* const* d_in, const int* in_sizes, int n_in,
                              void* d_out, int out_size, void* d_ws, size_t ws_size,
                              hipStream_t stream)
{
    const int*   x    = (const int*)  d_in[0];
    const int*   lens = (const int*)  d_in[1];
    const float* emb  = (const float*)d_in[2];
    const float* Wq   = (const float*)d_in[3];
    const float* bq   = (const float*)d_in[4];
    const float* Wk   = (const float*)d_in[5];
    const float* bk   = (const float*)d_in[6];
    const float* Wv   = (const float*)d_in[7];
    const float* bv   = (const float*)d_in[8];
    const float* W1   = (const float*)d_in[9];
    const float* b1   = (const float*)d_in[10];
    const float* W2   = (const float*)d_in[11];
    const float* b2   = (const float*)d_in[12];
    const float* g1   = (const float*)d_in[13];
    const float* be1  = (const float*)d_in[14];
    const float* g2   = (const float*)d_in[15];
    const float* be2  = (const float*)d_in[16];
    const float* fcw  = (const float*)d_in[17];
    const float* fcb  = (const float*)d_in[18];

    // Scratch in dead d_out region (everything dead before logits GEMM).
    float* out = (float*)d_out;
    float* Zb     = out;
    float* O1f    = Zb + NH;
    float* M2f    = O1f + NH;
    float* SCORES = M2f + NH;
    float* BQKV   = SCORES + SS8;                   // [L][2304]
    u16* ub   = (u16*)(BQKV + (long long)LAYERS * 2304);
    u16* Zbh  = ub;  ub += NH;
    u16* QKVh = ub;  ub += (long long)NROWS * 1536; // Q|K only, ldc 1536
    u16* ATTB = ub;  ub += SS8;
    u16* Vt   = ub;  ub += NH;                      // [B][H][S]
    u16* O1h  = ub;  ub += NH;
    u16* M1h  = ub;  ub += NH;
    u16* WT   = ub;  ub += 41LL * WSZ;              // [L][Wq|Wk|Wv|W1|W2] + fc

    u16* ZFh = (u16*)d_ws;                          // bf16 zf (survives logits)
    u16* EH  = ZFh + NH;                            // bf16 emb (if ws fits)
    const bool ehpath = ws_size >= (size_t)((NH + (long long)VOC * HID) * 2);

    const float scale = 1.0f / sqrtf((float)HID);
    const dim3 blk(256);

    embed_kernel<<<NROWS, blk, 0, stream>>>(x, emb, Zb, Zbh);
    transp_all<<<dim3(24, 24, 41), blk, 0, stream>>>(Wq, Wk, Wv, W1, W2, fcw, WT);
    pack_bias_all<<<dim3(3, LAYERS), dim3(768), 0, stream>>>(bq, bk, bv, BQKV);
    if (ehpath) convert_emb<<<7500, blk, 0, stream>>>(emb, EH);

    for (int l = 0; l < LAYERS; ++l) {
        const u16* wl = WT + (long long)l * 5 * WSZ;

        // qkv: Q,K -> QKVh[4096][1536]; V -> Vt[b][h][s] (transposed write)
        gemm_mfma<128, false, true, false, true><<<dim3(18, 32), blk, 0, stream>>>(
            Zbh, HID, 0, wl, HID, 0, QKVh, 1536, 0,
            2304, HID, BQKV + (long long)l * 2304, 1.0f, Vt);

        // scores = scale * Q @ K^T -> fp32 [b,512,512]
        gemm_mfma<64, false, false, false, false><<<dim3(8, 4, BATCH), blk, 0, stream>>>(
            QKVh, 1536, (long long)SEQ * 1536,
            QKVh + 768, 1536, (long long)SEQ * 1536,
            SCORES, SEQ, (long long)SEQ * SEQ,
            SEQ, HID, nullptr, scale, nullptr);

        softmax_q_kernel<<<dim3(BATCH, SEQ/64), blk, 0, stream>>>(SCORES, ATTB, lens);

        // attnout = att @ V  (B = Vt, already [N=h][K=s]) -> fp32
        gemm_mfma<64, false, false, false, false><<<dim3(12, 4, BATCH), blk, 0, stream>>>(
            ATTB, SEQ, (long long)SEQ * SEQ,
            Vt, SEQ, (long long)HID * SEQ,
            O1f, HID, (long long)SEQ * HID,
            HID, SEQ, nullptr, 1.0f, nullptr);

        ln_add_kernel<<<NROWS, blk, 0, stream>>>(Zb, O1f, O1f, O1h,
                                                 g1 + l*HID, be1 + l*HID);
        gemm_mfma<64, true, true, false, false><<<dim3(12, 32), blk, 0, stream>>>(
            O1h, HID, 0, wl + 3*WSZ, HID, 0, M1h, HID, 0,
            HID, HID, b1 + l*HID, 1.0f, nullptr);
        gemm_mfma<64, false, false, false, false><<<dim3(12, 32), blk, 0, stream>>>(
            M1h, HID, 0, wl + 4*WSZ, HID, 0, M2f, HID, 0,
            HID, HID, b2 + l*HID, 1.0f, nullptr);
        ln_add_kernel<<<NROWS, blk, 0, stream>>>(M2f, O1f, Zb, Zbh,
                                                 g2 + l*HID, be2 + l*HID);
    }

    // fc: zf = z @ fc_w + fc_b -> bf16 in d_ws
    gemm_mfma<64, false, true, false, false><<<dim3(12, 32), blk, 0, stream>>>(
        Zbh, HID, 0, WT + 40LL*WSZ, HID, 0, ZFh, HID, 0,
        HID, HID, fcb, 1.0f, nullptr);

    // logits = zf @ emb^T -> full d_out (scratch now dead). XISM grid:
    // consecutive blocks share the emb B-tile (L2 reuse).
    if (ehpath) {
        gemm_mfma<128, false, false, true, false><<<dim3(32, 79), blk, 0, stream>>>(
            ZFh, HID, 0, EH, HID, 0, out, VOC, 0,
            VOC, HID, nullptr, 1.0f, nullptr);
    } else {
        gemm_conv<<<dim3(32, 79), blk, 0, stream>>>(ZFh, emb, out);
    }

    softmax_v_kernel<<<NROWS, blk, 0, stream>>>(out);
}

// Round 4
// 1631.744 us; speedup vs baseline: 3.9689x; 1.0050x over previous
//
#include <hip/hip_runtime.h>
#include <math.h>

typedef unsigned int   u32;
typedef unsigned short u16;
typedef __attribute__((ext_vector_type(8))) short bf16x8;
typedef __attribute__((ext_vector_type(4))) float f32x4;
typedef __attribute__((ext_vector_type(4))) unsigned short u16x4;

#define HID   768
#define SEQ   512
#define BATCH 8
#define LAYERS 8
#define VOC   10000
#define NROWS (BATCH*SEQ)             // 4096
#define NH    ((long long)NROWS*HID)  // 3,145,728
#define SS8   ((long long)BATCH*SEQ*SEQ)
#define EPSLN 1e-5f
#define WSZ   ((long long)HID*HID)    // 589824

__device__ __forceinline__ u16 f2bf(float f) {
    u32 u = __builtin_bit_cast(u32, f);
    return (u16)((u + 0x7fffu + ((u >> 16) & 1u)) >> 16);
}

__device__ __forceinline__ void async16(u16* lds, const u16* g) {
    __builtin_amdgcn_global_load_lds(
        (const __attribute__((address_space(1))) u32*)g,
        (__attribute__((address_space(3))) u32*)lds, 16, 0, 0);
}

// ---- embedding + positional encoding (fp32 + bf16 shadow) ---------------
__global__ __launch_bounds__(256) void embed_kernel(
    const int* __restrict__ x, const float* __restrict__ emb,
    float* __restrict__ Z, u16* __restrict__ Zh)
{
    const int row = blockIdx.x;
    const int s   = row & (SEQ - 1);
    const int tok = x[row];
    const long long base  = (long long)row * HID;
    const long long ebase = (long long)tok * HID;
    const float coef = -0.0239852613853544f;   // -2*ln(10000)/768
    #pragma unroll
    for (int j = 0; j < 3; ++j) {
        const int h = threadIdx.x + 256 * j;
        const int i = h >> 1;
        const float ang = (float)s * expf((float)i * coef);
        const float pe  = (h & 1) ? cosf(ang) : sinf(ang);
        const float v = emb[ebase + h] + pe;
        Z[base + h]  = v;
        Zh[base + h] = f2bf(v);
    }
}

// ---- emb fp32 -> bf16, vectorized --------------------------------------
__global__ __launch_bounds__(256) void convert_emb(
    const float* __restrict__ e, u16* __restrict__ eh)
{
    const long long i = ((long long)blockIdx.x * 256 + threadIdx.x) * 4;
    const float4 v = *(const float4*)&e[i];
    u16x4 p;
    p[0] = f2bf(v.x); p[1] = f2bf(v.y); p[2] = f2bf(v.z); p[3] = f2bf(v.w);
    *(u16x4*)&eh[i] = p;
}

// ---- all-weights transpose+convert: fp32 [K,N] -> bf16 [N,K] ------------
__global__ __launch_bounds__(256) void transp_all(
    const float* __restrict__ Wq, const float* __restrict__ Wk,
    const float* __restrict__ Wv, const float* __restrict__ W1,
    const float* __restrict__ W2, const float* __restrict__ fcw,
    u16* __restrict__ WT)
{
    __shared__ u16 tile[32][34];
    const int z = blockIdx.z;
    const float* src;
    long long doff;
    if (z < 40) {
        const int lyr = z / 5, idx = z % 5;
        const float* bases[5] = {Wq, Wk, Wv, W1, W2};
        src  = bases[idx] + (long long)lyr * WSZ;
        doff = ((long long)lyr * 5 + idx) * WSZ;
    } else {
        src = fcw; doff = 40LL * WSZ;
    }
    u16* D = WT + doff;
    const int n0 = blockIdx.x * 32, k0 = blockIdx.y * 32;
    const int c = threadIdx.x & 31, r0 = threadIdx.x >> 5;
    #pragma unroll
    for (int p = 0; p < 4; ++p)
        tile[r0 + 8*p][c] = f2bf(src[(long long)(k0 + r0 + 8*p) * HID + n0 + c]);
    __syncthreads();
    #pragma unroll
    for (int p = 0; p < 4; ++p)
        D[(long long)(n0 + r0 + 8*p) * HID + k0 + c] = tile[c][r0 + 8*p];
}

// ---- pack qkv biases: [L][3*768] ---------------------------------------
__global__ void pack_bias_all(const float* __restrict__ bq,
                              const float* __restrict__ bk,
                              const float* __restrict__ bv,
                              float* __restrict__ dst)
{
    const int part = blockIdx.x, l = blockIdx.y, h = threadIdx.x;
    const float* src = part == 0 ? bq : (part == 1 ? bk : bv);
    dst[((long long)l*3 + part) * HID + h] = src[(long long)l*HID + h];
}

// ---- MFMA GEMM, 3-stage pipeline, counted vmcnt, LDS XOR-swizzle --------
// A: bf16 [M,K] k-contig. B: bf16 [N,K] k-contig. BM=128, 4 waves (2x2).
// Swizzle (rule 21, both sides): staging lane fetches global 16B-slot
// (l&3)^((l>>2)&3); reader of logical slot s in row r reads phys s^(r&3).
template<int BN, bool RELU, bool OUT_BF16, bool XISM, bool VSPLIT>
__global__ __launch_bounds__(256) void gemm_mfma(
    const u16* __restrict__ A, int lda, long long sA,
    const u16* __restrict__ B, int ldb, long long sB,
    void* __restrict__ Cp, int ldc, long long sC,
    int N, int K, const float* __restrict__ bias, float alpha,
    u16* __restrict__ vt)
{
    constexpr int NI = BN / 32;
    constexpr int LPT = 2 + BN / 64;          // per-thread loads per K-tile
    __shared__ u16 As[3][128 * 32];
    __shared__ u16 Bs[3][BN * 32];
    const int bz = blockIdx.z;
    const int m0 = (XISM ? blockIdx.x : blockIdx.y) * 128;
    const int n0 = (XISM ? blockIdx.y : blockIdx.x) * BN;
    const int t = threadIdx.x, w = t >> 6, l = t & 63;
    const int lrow = l >> 2;
    const int lswz = ((l & 3) ^ (lrow & 3)) * 8;   // pre-swizzled k-slot
    const int wm = (w >> 1) * 64, wn = (w & 1) * (BN / 2);
    A += sA * bz; B += sB * bz;

    f32x4 acc[4][NI];
    #pragma unroll
    for (int mi = 0; mi < 4; ++mi)
        #pragma unroll
        for (int ni = 0; ni < NI; ++ni) acc[mi][ni] = (f32x4){0.f,0.f,0.f,0.f};

    auto stage = [&](int buf, int k0) {
        #pragma unroll
        for (int r = 0; r < 2; ++r) {
            const int seg = w * 2 + r;
            async16(&As[buf][seg * 512],
                    A + (long long)(m0 + seg*16 + lrow) * lda + (k0 + lswz));
        }
        #pragma unroll
        for (int r = 0; r < BN / 64; ++r) {
            const int seg = w + r * 4;
            int row = n0 + seg*16 + lrow;
            row = row < N ? row : N - 1;
            async16(&Bs[buf][seg * 512], B + (long long)row * ldb + (k0 + lswz));
        }
    };
    const int fr = l & 15, fkb = l >> 4;           // logical 16B slot 0..3
    const int psl = (fkb ^ (fr & 3)) * 8;          // physical slot (u16 units)
    auto compute = [&](int cur) {
        bf16x8 af[4], bfr[NI];
        #pragma unroll
        for (int mi = 0; mi < 4; ++mi)
            af[mi] = *(const bf16x8*)&As[cur][(wm + mi*16 + fr) * 32 + psl];
        #pragma unroll
        for (int ni = 0; ni < NI; ++ni)
            bfr[ni] = *(const bf16x8*)&Bs[cur][(wn + ni*16 + fr) * 32 + psl];
        #pragma unroll
        for (int mi = 0; mi < 4; ++mi)
            #pragma unroll
            for (int ni = 0; ni < NI; ++ni)
                acc[mi][ni] = __builtin_amdgcn_mfma_f32_16x16x32_bf16(
                    af[mi], bfr[ni], acc[mi][ni], 0, 0, 0);
    };

    const int NS = K >> 5;                // K-tiles (24 or 16)
    stage(0, 0);
    if (NS > 1) stage(1, 32);
    int cur = 0, nxt = 2;
    for (int tt = 0; tt < NS; ++tt) {
        if (tt + 1 < NS)
            asm volatile("s_waitcnt vmcnt(%0)\n\ts_barrier" :: "i"(LPT) : "memory");
        else
            asm volatile("s_waitcnt vmcnt(0)\n\ts_barrier" ::: "memory");
        if (tt + 2 < NS) stage(nxt, (tt + 2) << 5);
        compute(cur);
        cur = (cur == 2) ? 0 : cur + 1;
        nxt = (nxt == 2) ? 0 : nxt + 1;
    }

    float* Cf = (float*)Cp + sC * bz;
    u16*   Ch = (u16*)Cp + sC * bz;
    const int fq = l >> 4;
    #pragma unroll
    for (int ni = 0; ni < NI; ++ni) {
        const int col = n0 + wn + ni*16 + fr;
        const bool ok = col < N;
        const float bv = (bias && ok) ? bias[col] : 0.f;
        #pragma unroll
        for (int mi = 0; mi < 4; ++mi) {
            const int row0 = m0 + wm + mi*16 + fq*4;
            if constexpr (VSPLIT) {
                if (col < 1536) {
                    #pragma unroll
                    for (int v = 0; v < 4; ++v)
                        Ch[(long long)(row0 + v) * ldc + col] =
                            f2bf(alpha * acc[mi][ni][v] + bv);
                } else {
                    const int b9 = row0 >> 9, s9 = row0 & 511;
                    u16x4 pk;
                    #pragma unroll
                    for (int v = 0; v < 4; ++v)
                        pk[v] = f2bf(alpha * acc[mi][ni][v] + bv);
                    *(u16x4*)&vt[((long long)b9 * HID + (col - 1536)) * SEQ + s9] = pk;
                }
            } else {
                #pragma unroll
                for (int v = 0; v < 4; ++v) {
                    float val = alpha * acc[mi][ni][v] + bv;
                    if (RELU) val = fmaxf(val, 0.f);
                    if (ok) {
                        if (OUT_BF16) Ch[(long long)(row0 + v) * ldc + col] = f2bf(val);
                        else          Cf[(long long)(row0 + v) * ldc + col] = val;
                    }
                }
            }
        }
    }
}

// ---- fallback logits GEMM (fp32 B converted in-flight) ------------------
__global__ __launch_bounds__(256) void gemm_conv(
    const u16* __restrict__ A, const float* __restrict__ Bf,
    float* __restrict__ C)
{
    __shared__ u16 As[128 * 32];
    __shared__ u16 Bs[128 * 32];
    const int m0 = blockIdx.x * 128;
    const int n0 = blockIdx.y * 128;
    const int t = threadIdx.x, w = t >> 6, l = t & 63;
    const int lrow = l >> 2, lk8 = (l & 3) * 8;
    const int wm = (w >> 1) * 64, wn = (w & 1) * 64;
    f32x4 acc[4][4];
    #pragma unroll
    for (int mi = 0; mi < 4; ++mi)
        #pragma unroll
        for (int ni = 0; ni < 4; ++ni) acc[mi][ni] = (f32x4){0.f,0.f,0.f,0.f};

    for (int k0 = 0; k0 < HID; k0 += 32) {
        #pragma unroll
        for (int r = 0; r < 2; ++r) {
            const int seg = w * 2 + r;
            async16(&As[seg * 512],
                    A + (long long)(m0 + seg*16 + lrow) * HID + (k0 + lk8));
        }
        #pragma unroll
        for (int r = 0; r < 2; ++r) {
            const int flat = r * 2048 + t * 8;
            int row = n0 + (flat >> 5);
            row = row < VOC ? row : VOC - 1;
            const float* g = Bf + (long long)row * HID + (k0 + (flat & 31));
            const float4 v0 = *(const float4*)g;
            const float4 v1 = *(const float4*)(g + 4);
            bf16x8 hv;
            hv[0]=(short)f2bf(v0.x); hv[1]=(short)f2bf(v0.y);
            hv[2]=(short)f2bf(v0.z); hv[3]=(short)f2bf(v0.w);
            hv[4]=(short)f2bf(v1.x); hv[5]=(short)f2bf(v1.y);
            hv[6]=(short)f2bf(v1.z); hv[7]=(short)f2bf(v1.w);
            *(bf16x8*)&Bs[flat] = hv;
        }
        __syncthreads();
        const int fr = l & 15, fk = (l >> 4) * 8;
        bf16x8 af[4], bfr[4];
        #pragma unroll
        for (int mi = 0; mi < 4; ++mi)
            af[mi] = *(const bf16x8*)&As[(wm + mi*16 + fr) * 32 + fk];
        #pragma unroll
        for (int ni = 0; ni < 4; ++ni)
            bfr[ni] = *(const bf16x8*)&Bs[(wn + ni*16 + fr) * 32 + fk];
        #pragma unroll
        for (int mi = 0; mi < 4; ++mi)
            #pragma unroll
            for (int ni = 0; ni < 4; ++ni)
                acc[mi][ni] = __builtin_amdgcn_mfma_f32_16x16x32_bf16(
                    af[mi], bfr[ni], acc[mi][ni], 0, 0, 0);
        __syncthreads();
    }
    const int fr = l & 15, fq = l >> 4;
    #pragma unroll
    for (int ni = 0; ni < 4; ++ni) {
        const int col = n0 + wn + ni*16 + fr;
        if (col >= VOC) continue;
        #pragma unroll
        for (int mi = 0; mi < 4; ++mi) {
            const int row0 = m0 + wm + mi*16 + fq*4;
            #pragma unroll
            for (int v = 0; v < 4; ++v)
                C[(long long)(row0 + v) * VOC + col] = acc[mi][ni][v];
        }
    }
}

// ---- masked softmax over the QUERY axis (dim=1): fp32 in, bf16 out ------
__global__ __launch_bounds__(256) void softmax_q_kernel(
    const float* __restrict__ sc, u16* __restrict__ att,
    const int* __restrict__ lengths)
{
    const int b  = blockIdx.x;
    const int k0 = blockIdx.y * 64;
    const int tx = threadIdx.x & 63;
    const int ty = threadIdx.x >> 6;
    const int c  = k0 + tx;
    const int len = lengths[b];
    const float* base  = sc  + (long long)b * SEQ * SEQ;
    u16*         obase = att + (long long)b * SEQ * SEQ;
    const bool cvalid = (c < len);

    float m = -3.0e38f, ssum = 0.f;
    for (int q = ty; q < SEQ; q += 4) {
        if (cvalid && c <= q && q < len) {
            const float xv = base[(long long)q * SEQ + c];
            if (xv > m) { ssum = ssum * __expf(m - xv) + 1.f; m = xv; }
            else        { ssum += __expf(xv - m); }
        }
    }
    __shared__ float ms[4][64], ss[4][64];
    ms[ty][tx] = m; ss[ty][tx] = ssum;
    __syncthreads();
    if (ty == 0) {
        float M = ms[0][tx];
        #pragma unroll
        for (int r = 1; r < 4; ++r) M = fmaxf(M, ms[r][tx]);
        float Sx = 0.f;
        #pragma unroll
        for (int r = 0; r < 4; ++r) Sx += ss[r][tx] * __expf(ms[r][tx] - M);
        ms[0][tx] = M; ss[0][tx] = Sx;
    }
    __syncthreads();
    const float M   = ms[0][tx];
    const float den = ss[0][tx];
    const float inv = (den > 0.f) ? 1.f / den : 0.f;
    for (int q = ty; q < SEQ; q += 4) {
        const long long idx = (long long)q * SEQ + c;
        float o = 0.f;
        if (cvalid && c <= q && q < len) o = __expf(base[idx] - M) * inv;
        obase[idx] = f2bf(o);
    }
}

// ---- fused residual-add + LayerNorm, fp32 + bf16 outputs ---------------
__global__ __launch_bounds__(256) void ln_add_kernel(
    const float* __restrict__ Xa, const float* __restrict__ Xb,
    float* __restrict__ O, u16* __restrict__ Oh,
    const float* __restrict__ g, const float* __restrict__ be)
{
    const int row = blockIdx.x;
    const long long base = (long long)row * HID;
    const int t = threadIdx.x;
    const float x0 = Xa[base + t]       + Xb[base + t];
    const float x1 = Xa[base + t + 256] + Xb[base + t + 256];
    const float x2 = Xa[base + t + 512] + Xb[base + t + 512];
    __shared__ float r1[4], r2[4];
    float s = x0 + x1 + x2;
    #pragma unroll
    for (int o = 32; o; o >>= 1) s += __shfl_down(s, o, 64);
    if ((t & 63) == 0) r1[t >> 6] = s;
    __syncthreads();
    const float mean = (r1[0] + r1[1] + r1[2] + r1[3]) * (1.f / HID);
    const float d0 = x0 - mean, d1 = x1 - mean, d2 = x2 - mean;
    float v = d0*d0 + d1*d1 + d2*d2;
    #pragma unroll
    for (int o = 32; o; o >>= 1) v += __shfl_down(v, o, 64);
    if ((t & 63) == 0) r2[t >> 6] = v;
    __syncthreads();
    const float var = (r2[0] + r2[1] + r2[2] + r2[3]) * (1.f / HID);
    const float rs = rsqrtf(var + EPSLN);
    const float y0 = d0 * rs * g[t]       + be[t];
    const float y1 = d1 * rs * g[t + 256] + be[t + 256];
    const float y2 = d2 * rs * g[t + 512] + be[t + 512];
    O[base + t]        = y0;  Oh[base + t]       = f2bf(y0);
    O[base + t + 256]  = y1;  Oh[base + t + 256] = f2bf(y1);
    O[base + t + 512]  = y2;  Oh[base + t + 512] = f2bf(y2);
}

// ---- vocab softmax: LDS row cache, one global read + one write ----------
__global__ __launch_bounds__(256) void softmax_v_kernel(float* __restrict__ out)
{
    __shared__ float row[VOC];            // 40 KB
    __shared__ float rm[4], rs_[4];
    float4* o4 = (float4*)(out + (long long)blockIdx.x * VOC);
    const int t = threadIdx.x;
    float m = -3.0e38f, s = 0.f;
    for (int i = t; i < VOC/4; i += 256) {
        const float4 v = o4[i];
        *(float4*)&row[i*4] = v;          // private stripe: no cross-thread dep
        #pragma unroll
        for (int j = 0; j < 4; ++j) {
            const float xv = j==0?v.x:(j==1?v.y:(j==2?v.z:v.w));
            const float d = xv - m;
            if (d > 0.f) { s = s * __expf(-d) + 1.f; m = xv; }
            else         { s += __expf(d); }
        }
    }
    #pragma unroll
    for (int o = 32; o; o >>= 1) {
        const float om = __shfl_down(m, o, 64), os = __shfl_down(s, o, 64);
        const float M = fmaxf(m, om);
        s = s * __expf(m - M) + os * __expf(om - M);
        m = M;
    }
    if ((t & 63) == 0) { rm[t >> 6] = m; rs_[t >> 6] = s; }
    __syncthreads();
    const float M = fmaxf(fmaxf(rm[0], rm[1]), fmaxf(rm[2], rm[3]));
    const float S = rs_[0]*__expf(rm[0]-M) + rs_[1]*__expf(rm[1]-M)
                  + rs_[2]*__expf(rm[2]-M) + rs_[3]*__expf(rm[3]-M);
    const float inv = 1.f / S;
    for (int i = t; i < VOC/4; i += 256) {
        float4 v = *(const float4*)&row[i*4];
        v.x = __expf(v.x - M) * inv;
        v.y = __expf(v.y - M) * inv;
        v.z = __expf(v.z - M) * inv;
        v.w = __expf(v.w - M) * inv;
        o4[i] = v;
    }
}

// ---- host-side orchestration -------------------------------------------
extern "C" void kernel_launch(void* const* d_in, const int* in_sizes, int n_in,
                              void* d_out, int out_size, void* d_ws, size_t ws_size,
                              hipStream_t stream)
{
    const int*   x    = (const int*)  d_in[0];
    const int*   lens = (const int*)  d_in[1];
    const float* emb  = (const float*)d_in[2];
    const float* Wq   = (const float*)d_in[3];
    const float* bq   = (const float*)d_in[4];
    const float* Wk   = (const float*)d_in[5];
    const float* bk   = (const float*)d_in[6];
    const float* Wv   = (const float*)d_in[7];
    const float* bv   = (const float*)d_in[8];
    const float* W1   = (const float*)d_in[9];
    const float* b1   = (const float*)d_in[10];
    const float* W2   = (const float*)d_in[11];
    const float* b2   = (const float*)d_in[12];
    const float* g1   = (const float*)d_in[13];
    const float* be1  = (const float*)d_in[14];
    const float* g2   = (const float*)d_in[15];
    const float* be2  = (const float*)d_in[16];
    const float* fcw  = (const float*)d_in[17];
    const float* fcb  = (const float*)d_in[18];

    float* out = (float*)d_out;
    float* Zb     = out;
    float* O1f    = Zb + NH;
    float* M2f    = O1f + NH;
    float* SCORES = M2f + NH;
    float* BQKV   = SCORES + SS8;                   // [L][2304]
    u16* ub   = (u16*)(BQKV + (long long)LAYERS * 2304);
    u16* Zbh  = ub;  ub += NH;
    u16* QKVh = ub;  ub += (long long)NROWS * 1536; // Q|K, ldc 1536
    u16* ATTB = ub;  ub += SS8;
    u16* Vt   = ub;  ub += NH;                      // [B][H][S]
    u16* O1h  = ub;  ub += NH;
    u16* M1h  = ub;  ub += NH;
    u16* WT   = ub;  ub += 41LL * WSZ;

    u16* ZFh = (u16*)d_ws;
    u16* EH  = ZFh + NH;
    const bool ehpath = ws_size >= (size_t)((NH + (long long)VOC * HID) * 2);

    const float scale = 1.0f / sqrtf((float)HID);
    const dim3 blk(256);

    embed_kernel<<<NROWS, blk, 0, stream>>>(x, emb, Zb, Zbh);
    transp_all<<<dim3(24, 24, 41), blk, 0, stream>>>(Wq, Wk, Wv, W1, W2, fcw, WT);
    pack_bias_all<<<dim3(3, LAYERS), dim3(768), 0, stream>>>(bq, bk, bv, BQKV);
    if (ehpath) convert_emb<<<7500, blk, 0, stream>>>(emb, EH);

    for (int l = 0; l < LAYERS; ++l) {
        const u16* wl = WT + (long long)l * 5 * WSZ;

        gemm_mfma<128, false, true, false, true><<<dim3(18, 32), blk, 0, stream>>>(
            Zbh, HID, 0, wl, HID, 0, QKVh, 1536, 0,
            2304, HID, BQKV + (long long)l * 2304, 1.0f, Vt);

        gemm_mfma<64, false, false, false, false><<<dim3(8, 4, BATCH), blk, 0, stream>>>(
            QKVh, 1536, (long long)SEQ * 1536,
            QKVh + 768, 1536, (long long)SEQ * 1536,
            SCORES, SEQ, (long long)SEQ * SEQ,
            SEQ, HID, nullptr, scale, nullptr);

        softmax_q_kernel<<<dim3(BATCH, SEQ/64), blk, 0, stream>>>(SCORES, ATTB, lens);

        gemm_mfma<64, false, false, false, false><<<dim3(12, 4, BATCH), blk, 0, stream>>>(
            ATTB, SEQ, (long long)SEQ * SEQ,
            Vt, SEQ, (long long)HID * SEQ,
            O1f, HID, (long long)SEQ * HID,
            HID, SEQ, nullptr, 1.0f, nullptr);

        ln_add_kernel<<<NROWS, blk, 0, stream>>>(Zb, O1f, O1f, O1h,
                                                 g1 + l*HID, be1 + l*HID);
        gemm_mfma<64, true, true, false, false><<<dim3(12, 32), blk, 0, stream>>>(
            O1h, HID, 0, wl + 3*WSZ, HID, 0, M1h, HID, 0,
            HID, HID, b1 + l*HID, 1.0f, nullptr);
        gemm_mfma<64, false, false, false, false><<<dim3(12, 32), blk, 0, stream>>>(
            M1h, HID, 0, wl + 4*WSZ, HID, 0, M2f, HID, 0,
            HID, HID, b2 + l*HID, 1.0f, nullptr);
        ln_add_kernel<<<NROWS, blk, 0, stream>>>(M2f, O1f, Zb, Zbh,
                                                 g2 + l*HID, be2 + l*HID);
    }

    gemm_mfma<64, false, true, false, false><<<dim3(12, 32), blk, 0, stream>>>(
        Zbh, HID, 0, WT + 40LL*WSZ, HID, 0, ZFh, HID, 0,
        HID, HID, fcb, 1.0f, nullptr);

    if (ehpath) {
        gemm_mfma<128, false, false, true, false><<<dim3(32, 79), blk, 0, stream>>>(
            ZFh, HID, 0, EH, HID, 0, out, VOC, 0,
            VOC, HID, nullptr, 1.0f, nullptr);
    } else {
        gemm_conv<<<dim3(32, 79), blk, 0, stream>>>(ZFh, emb, out);
    }

    softmax_v_kernel<<<NROWS, blk, 0, stream>>>(out);
}

// Round 5
// 1247.616 us; speedup vs baseline: 5.1909x; 1.3079x over previous
//
#include <hip/hip_runtime.h>
#include <math.h>

typedef unsigned int   u32;
typedef unsigned short u16;
typedef __attribute__((ext_vector_type(8))) short bf16x8;
typedef __attribute__((ext_vector_type(4))) float f32x4;
typedef __attribute__((ext_vector_type(4))) unsigned short u16x4;

#define HID   768
#define SEQ   512
#define BATCH 8
#define LAYERS 8
#define VOC   10000
#define NROWS (BATCH*SEQ)             // 4096
#define NH    ((long long)NROWS*HID)  // 3,145,728
#define SS8   ((long long)BATCH*SEQ*SEQ)
#define EPSLN 1e-5f
#define WSZ   ((long long)HID*HID)    // 589824

__device__ __forceinline__ u16 f2bf(float f) {
    u32 u = __builtin_bit_cast(u32, f);
    return (u16)((u + 0x7fffu + ((u >> 16) & 1u)) >> 16);
}

__device__ __forceinline__ void async16(u16* lds, const u16* g) {
    __builtin_amdgcn_global_load_lds(
        (const __attribute__((address_space(1))) u32*)g,
        (__attribute__((address_space(3))) u32*)lds, 16, 0, 0);
}

// ---- embedding + positional encoding (fp32 + bf16 shadow) ---------------
__global__ __launch_bounds__(256) void embed_kernel(
    const int* __restrict__ x, const float* __restrict__ emb,
    float* __restrict__ Z, u16* __restrict__ Zh)
{
    const int row = blockIdx.x;
    const int s   = row & (SEQ - 1);
    const int tok = x[row];
    const long long base  = (long long)row * HID;
    const long long ebase = (long long)tok * HID;
    const float coef = -0.0239852613853544f;   // -2*ln(10000)/768
    #pragma unroll
    for (int j = 0; j < 3; ++j) {
        const int h = threadIdx.x + 256 * j;
        const int i = h >> 1;
        const float ang = (float)s * expf((float)i * coef);
        const float pe  = (h & 1) ? cosf(ang) : sinf(ang);
        const float v = emb[ebase + h] + pe;
        Z[base + h]  = v;
        Zh[base + h] = f2bf(v);
    }
}

// ---- emb fp32 -> bf16, vectorized --------------------------------------
__global__ __launch_bounds__(256) void convert_emb(
    const float* __restrict__ e, u16* __restrict__ eh)
{
    const long long i = ((long long)blockIdx.x * 256 + threadIdx.x) * 4;
    const float4 v = *(const float4*)&e[i];
    u16x4 p;
    p[0] = f2bf(v.x); p[1] = f2bf(v.y); p[2] = f2bf(v.z); p[3] = f2bf(v.w);
    *(u16x4*)&eh[i] = p;
}

// ---- all-weights transpose+convert: fp32 [K,N] -> bf16 [N,K] ------------
__global__ __launch_bounds__(256) void transp_all(
    const float* __restrict__ Wq, const float* __restrict__ Wk,
    const float* __restrict__ Wv, const float* __restrict__ W1,
    const float* __restrict__ W2, const float* __restrict__ fcw,
    u16* __restrict__ WT)
{
    __shared__ u16 tile[32][34];
    const int z = blockIdx.z;
    const float* src;
    long long doff;
    if (z < 40) {
        const int lyr = z / 5, idx = z % 5;
        const float* bases[5] = {Wq, Wk, Wv, W1, W2};
        src  = bases[idx] + (long long)lyr * WSZ;
        doff = ((long long)lyr * 5 + idx) * WSZ;
    } else {
        src = fcw; doff = 40LL * WSZ;
    }
    u16* D = WT + doff;
    const int n0 = blockIdx.x * 32, k0 = blockIdx.y * 32;
    const int c = threadIdx.x & 31, r0 = threadIdx.x >> 5;
    #pragma unroll
    for (int p = 0; p < 4; ++p)
        tile[r0 + 8*p][c] = f2bf(src[(long long)(k0 + r0 + 8*p) * HID + n0 + c]);
    __syncthreads();
    #pragma unroll
    for (int p = 0; p < 4; ++p)
        D[(long long)(n0 + r0 + 8*p) * HID + k0 + c] = tile[c][r0 + 8*p];
}

// ---- pack qkv biases: [L][3*768] ---------------------------------------
__global__ void pack_bias_all(const float* __restrict__ bq,
                              const float* __restrict__ bk,
                              const float* __restrict__ bv,
                              float* __restrict__ dst)
{
    const int part = blockIdx.x, l = blockIdx.y, h = threadIdx.x;
    const float* src = part == 0 ? bq : (part == 1 ? bk : bv);
    dst[((long long)l*3 + part) * HID + h] = src[(long long)l*HID + h];
}

// ---- MFMA GEMM, 2-buffer counted-vmcnt pipeline -------------------------
// A: bf16 [M,K] k-contig. B: bf16 [N,K] k-contig. Waves: WM x WN grid, wave
// tile (BM/WM) x (BN/WN). Loads never drain to vmcnt(0) mid-loop (T4).
// XISM: blockIdx.x indexes M. VSPLIT: cols>=1536 written transposed to vt.
template<int BM, int BN, int WM, int WN, bool RELU, bool OUT_BF16, bool XISM, bool VSPLIT>
__global__ __launch_bounds__(WM*WN*64) void gemm_mfma(
    const u16* __restrict__ A, int lda, long long sA,
    const u16* __restrict__ B, int ldb, long long sB,
    void* __restrict__ Cp, int ldc, long long sC,
    int N, int K, const float* __restrict__ bias, float alpha,
    u16* __restrict__ vt)
{
    constexpr int NW  = WM * WN;
    constexpr int MI  = BM / WM / 16;
    constexpr int NI  = BN / WN / 16;
    constexpr int APW = BM / 16 / NW;      // A segs per wave
    constexpr int BPW = BN / 16 / NW;      // B segs per wave
    constexpr int LPT = APW + BPW;         // loads in flight per thread/tile
    __shared__ u16 As[2][BM * 32];
    __shared__ u16 Bs[2][BN * 32];
    const int bz = blockIdx.z;
    const int m0 = (XISM ? blockIdx.x : blockIdx.y) * BM;
    const int n0 = (XISM ? blockIdx.y : blockIdx.x) * BN;
    const int t = threadIdx.x, w = t >> 6, l = t & 63;
    const int lrow = l >> 2, lk8 = (l & 3) * 8;
    const int wm = (w / WN) * (BM / WM);
    const int wn = (w % WN) * (BN / WN);
    A += sA * bz; B += sB * bz;

    f32x4 acc[MI][NI];
    #pragma unroll
    for (int mi = 0; mi < MI; ++mi)
        #pragma unroll
        for (int ni = 0; ni < NI; ++ni) acc[mi][ni] = (f32x4){0.f,0.f,0.f,0.f};

    auto stage = [&](int buf, int k0) {
        #pragma unroll
        for (int r = 0; r < APW; ++r) {
            const int seg = w * APW + r;
            async16(&As[buf][seg * 512],
                    A + (long long)(m0 + seg*16 + lrow) * lda + (k0 + lk8));
        }
        #pragma unroll
        for (int r = 0; r < BPW; ++r) {
            const int seg = w * BPW + r;
            int row = n0 + seg*16 + lrow;
            row = row < N ? row : N - 1;
            async16(&Bs[buf][seg * 512], B + (long long)row * ldb + (k0 + lk8));
        }
    };
    const int fr = l & 15, fk = (l >> 4) * 8;
    auto compute = [&](int cur) {
        bf16x8 af[MI], bfr[NI];
        #pragma unroll
        for (int mi = 0; mi < MI; ++mi)
            af[mi] = *(const bf16x8*)&As[cur][(wm + mi*16 + fr) * 32 + fk];
        #pragma unroll
        for (int ni = 0; ni < NI; ++ni)
            bfr[ni] = *(const bf16x8*)&Bs[cur][(wn + ni*16 + fr) * 32 + fk];
        #pragma unroll
        for (int mi = 0; mi < MI; ++mi)
            #pragma unroll
            for (int ni = 0; ni < NI; ++ni)
                acc[mi][ni] = __builtin_amdgcn_mfma_f32_16x16x32_bf16(
                    af[mi], bfr[ni], acc[mi][ni], 0, 0, 0);
    };

    const int NS = K >> 5;
    stage(0, 0);
    for (int tt = 0; tt < NS; ++tt) {
        if (tt + 1 < NS) {
            stage((tt + 1) & 1, (tt + 1) << 5);   // next tile in flight
            asm volatile("s_waitcnt vmcnt(%0)\n\ts_barrier" :: "i"(LPT) : "memory");
        } else {
            asm volatile("s_waitcnt vmcnt(0)\n\ts_barrier" ::: "memory");
        }
        compute(tt & 1);
        asm volatile("s_barrier" ::: "memory");  // protect buf before re-stage
    }

    float* Cf = (float*)Cp + sC * bz;
    u16*   Ch = (u16*)Cp + sC * bz;
    const int fq = l >> 4;
    #pragma unroll
    for (int ni = 0; ni < NI; ++ni) {
        const int col = n0 + wn + ni*16 + fr;
        const bool ok = col < N;
        const float bv = (bias && ok) ? bias[col] : 0.f;
        #pragma unroll
        for (int mi = 0; mi < MI; ++mi) {
            const int row0 = m0 + wm + mi*16 + fq*4;
            if constexpr (VSPLIT) {
                if (col < 1536) {
                    #pragma unroll
                    for (int v = 0; v < 4; ++v)
                        Ch[(long long)(row0 + v) * ldc + col] =
                            f2bf(alpha * acc[mi][ni][v] + bv);
                } else {
                    const int b9 = row0 >> 9, s9 = row0 & 511;
                    u16x4 pk;
                    #pragma unroll
                    for (int v = 0; v < 4; ++v)
                        pk[v] = f2bf(alpha * acc[mi][ni][v] + bv);
                    *(u16x4*)&vt[((long long)b9 * HID + (col - 1536)) * SEQ + s9] = pk;
                }
            } else {
                #pragma unroll
                for (int v = 0; v < 4; ++v) {
                    float val = alpha * acc[mi][ni][v] + bv;
                    if (RELU) val = fmaxf(val, 0.f);
                    if (ok) {
                        if (OUT_BF16) Ch[(long long)(row0 + v) * ldc + col] = f2bf(val);
                        else          Cf[(long long)(row0 + v) * ldc + col] = val;
                    }
                }
            }
        }
    }
}

// ---- fallback logits GEMM (fp32 B converted in-flight) ------------------
__global__ __launch_bounds__(256) void gemm_conv(
    const u16* __restrict__ A, const float* __restrict__ Bf,
    float* __restrict__ C)
{
    __shared__ u16 As[128 * 32];
    __shared__ u16 Bs[128 * 32];
    const int m0 = blockIdx.x * 128;
    const int n0 = blockIdx.y * 128;
    const int t = threadIdx.x, w = t >> 6, l = t & 63;
    const int lrow = l >> 2, lk8 = (l & 3) * 8;
    const int wm = (w >> 1) * 64, wn = (w & 1) * 64;
    f32x4 acc[4][4];
    #pragma unroll
    for (int mi = 0; mi < 4; ++mi)
        #pragma unroll
        for (int ni = 0; ni < 4; ++ni) acc[mi][ni] = (f32x4){0.f,0.f,0.f,0.f};

    for (int k0 = 0; k0 < HID; k0 += 32) {
        #pragma unroll
        for (int r = 0; r < 2; ++r) {
            const int seg = w * 2 + r;
            async16(&As[seg * 512],
                    A + (long long)(m0 + seg*16 + lrow) * HID + (k0 + lk8));
        }
        #pragma unroll
        for (int r = 0; r < 2; ++r) {
            const int flat = r * 2048 + t * 8;
            int row = n0 + (flat >> 5);
            row = row < VOC ? row : VOC - 1;
            const float* g = Bf + (long long)row * HID + (k0 + (flat & 31));
            const float4 v0 = *(const float4*)g;
            const float4 v1 = *(const float4*)(g + 4);
            bf16x8 hv;
            hv[0]=(short)f2bf(v0.x); hv[1]=(short)f2bf(v0.y);
            hv[2]=(short)f2bf(v0.z); hv[3]=(short)f2bf(v0.w);
            hv[4]=(short)f2bf(v1.x); hv[5]=(short)f2bf(v1.y);
            hv[6]=(short)f2bf(v1.z); hv[7]=(short)f2bf(v1.w);
            *(bf16x8*)&Bs[flat] = hv;
        }
        __syncthreads();
        const int fr = l & 15, fk = (l >> 4) * 8;
        bf16x8 af[4], bfr[4];
        #pragma unroll
        for (int mi = 0; mi < 4; ++mi)
            af[mi] = *(const bf16x8*)&As[(wm + mi*16 + fr) * 32 + fk];
        #pragma unroll
        for (int ni = 0; ni < 4; ++ni)
            bfr[ni] = *(const bf16x8*)&Bs[(wn + ni*16 + fr) * 32 + fk];
        #pragma unroll
        for (int mi = 0; mi < 4; ++mi)
            #pragma unroll
            for (int ni = 0; ni < 4; ++ni)
                acc[mi][ni] = __builtin_amdgcn_mfma_f32_16x16x32_bf16(
                    af[mi], bfr[ni], acc[mi][ni], 0, 0, 0);
        __syncthreads();
    }
    const int fr = l & 15, fq = l >> 4;
    #pragma unroll
    for (int ni = 0; ni < 4; ++ni) {
        const int col = n0 + wn + ni*16 + fr;
        if (col >= VOC) continue;
        #pragma unroll
        for (int mi = 0; mi < 4; ++mi) {
            const int row0 = m0 + wm + mi*16 + fq*4;
            #pragma unroll
            for (int v = 0; v < 4; ++v)
                C[(long long)(row0 + v) * VOC + col] = acc[mi][ni][v];
        }
    }
}

// ---- masked softmax over the QUERY axis (dim=1): fp32 in, bf16 out ------
// block 256 = 16 q-slices x 16 cols; grid (BATCH, SEQ/16) = (8,32)
__global__ __launch_bounds__(256) void softmax_q_kernel(
    const float* __restrict__ sc, u16* __restrict__ att,
    const int* __restrict__ lengths)
{
    const int b  = blockIdx.x;
    const int k0 = blockIdx.y * 16;
    const int tx = threadIdx.x & 15;
    const int ty = threadIdx.x >> 4;
    const int c  = k0 + tx;
    const int len = lengths[b];
    const float* base  = sc  + (long long)b * SEQ * SEQ;
    u16*         obase = att + (long long)b * SEQ * SEQ;
    const bool cvalid = (c < len);

    float m = -3.0e38f, ssum = 0.f;
    for (int q = ty; q < SEQ; q += 16) {
        if (cvalid && c <= q && q < len) {
            const float xv = base[(long long)q * SEQ + c];
            if (xv > m) { ssum = ssum * __expf(m - xv) + 1.f; m = xv; }
            else        { ssum += __expf(xv - m); }
        }
    }
    __shared__ float ms[16][17], ss[16][17];
    ms[ty][tx] = m; ss[ty][tx] = ssum;
    __syncthreads();
    if (ty == 0) {
        float M = ms[0][tx];
        #pragma unroll
        for (int r = 1; r < 16; ++r) M = fmaxf(M, ms[r][tx]);
        float Sx = 0.f;
        #pragma unroll
        for (int r = 0; r < 16; ++r) Sx += ss[r][tx] * __expf(ms[r][tx] - M);
        ms[0][tx] = M; ss[0][tx] = Sx;
    }
    __syncthreads();
    const float M   = ms[0][tx];
    const float den = ss[0][tx];
    const float inv = (den > 0.f) ? 1.f / den : 0.f;
    for (int q = ty; q < SEQ; q += 16) {
        const long long idx = (long long)q * SEQ + c;
        float o = 0.f;
        if (cvalid && c <= q && q < len) o = __expf(base[idx] - M) * inv;
        obase[idx] = f2bf(o);
    }
}

// ---- fused residual-add + LayerNorm, fp32 + bf16 outputs ---------------
__global__ __launch_bounds__(256) void ln_add_kernel(
    const float* __restrict__ Xa, const float* __restrict__ Xb,
    float* __restrict__ O, u16* __restrict__ Oh,
    const float* __restrict__ g, const float* __restrict__ be)
{
    const int row = blockIdx.x;
    const long long base = (long long)row * HID;
    const int t = threadIdx.x;
    const float x0 = Xa[base + t]       + Xb[base + t];
    const float x1 = Xa[base + t + 256] + Xb[base + t + 256];
    const float x2 = Xa[base + t + 512] + Xb[base + t + 512];
    __shared__ float r1[4], r2[4];
    float s = x0 + x1 + x2;
    #pragma unroll
    for (int o = 32; o; o >>= 1) s += __shfl_down(s, o, 64);
    if ((t & 63) == 0) r1[t >> 6] = s;
    __syncthreads();
    const float mean = (r1[0] + r1[1] + r1[2] + r1[3]) * (1.f / HID);
    const float d0 = x0 - mean, d1 = x1 - mean, d2 = x2 - mean;
    float v = d0*d0 + d1*d1 + d2*d2;
    #pragma unroll
    for (int o = 32; o; o >>= 1) v += __shfl_down(v, o, 64);
    if ((t & 63) == 0) r2[t >> 6] = v;
    __syncthreads();
    const float var = (r2[0] + r2[1] + r2[2] + r2[3]) * (1.f / HID);
    const float rs = rsqrtf(var + EPSLN);
    const float y0 = d0 * rs * g[t]       + be[t];
    const float y1 = d1 * rs * g[t + 256] + be[t + 256];
    const float y2 = d2 * rs * g[t + 512] + be[t + 512];
    O[base + t]        = y0;  Oh[base + t]       = f2bf(y0);
    O[base + t + 256]  = y1;  Oh[base + t + 256] = f2bf(y1);
    O[base + t + 512]  = y2;  Oh[base + t + 512] = f2bf(y2);
}

// ---- vocab softmax: LDS row cache, one global read + one write ----------
__global__ __launch_bounds__(256) void softmax_v_kernel(float* __restrict__ out)
{
    __shared__ float row[VOC];            // 40 KB
    __shared__ float rm[4], rs_[4];
    float4* o4 = (float4*)(out + (long long)blockIdx.x * VOC);
    const int t = threadIdx.x;
    float m = -3.0e38f, s = 0.f;
    for (int i = t; i < VOC/4; i += 256) {
        const float4 v = o4[i];
        *(float4*)&row[i*4] = v;
        #pragma unroll
        for (int j = 0; j < 4; ++j) {
            const float xv = j==0?v.x:(j==1?v.y:(j==2?v.z:v.w));
            const float d = xv - m;
            if (d > 0.f) { s = s * __expf(-d) + 1.f; m = xv; }
            else         { s += __expf(d); }
        }
    }
    #pragma unroll
    for (int o = 32; o; o >>= 1) {
        const float om = __shfl_down(m, o, 64), os = __shfl_down(s, o, 64);
        const float M = fmaxf(m, om);
        s = s * __expf(m - M) + os * __expf(om - M);
        m = M;
    }
    if ((t & 63) == 0) { rm[t >> 6] = m; rs_[t >> 6] = s; }
    __syncthreads();
    const float M = fmaxf(fmaxf(rm[0], rm[1]), fmaxf(rm[2], rm[3]));
    const float S = rs_[0]*__expf(rm[0]-M) + rs_[1]*__expf(rm[1]-M)
                  + rs_[2]*__expf(rm[2]-M) + rs_[3]*__expf(rm[3]-M);
    const float inv = 1.f / S;
    for (int i = t; i < VOC/4; i += 256) {
        float4 v = *(const float4*)&row[i*4];
        v.x = __expf(v.x - M) * inv;
        v.y = __expf(v.y - M) * inv;
        v.z = __expf(v.z - M) * inv;
        v.w = __expf(v.w - M) * inv;
        o4[i] = v;
    }
}

// ---- host-side orchestration -------------------------------------------
extern "C" void kernel_launch(void* const* d_in, const int* in_sizes, int n_in,
                              void* d_out, int out_size, void* d_ws, size_t ws_size,
                              hipStream_t stream)
{
    const int*   x    = (const int*)  d_in[0];
    const int*   lens = (const int*)  d_in[1];
    const float* emb  = (const float*)d_in[2];
    const float* Wq   = (const float*)d_in[3];
    const float* bq   = (const float*)d_in[4];
    const float* Wk   = (const float*)d_in[5];
    const float* bk   = (const float*)d_in[6];
    const float* Wv   = (const float*)d_in[7];
    const float* bv   = (const float*)d_in[8];
    const float* W1   = (const float*)d_in[9];
    const float* b1   = (const float*)d_in[10];
    const float* W2   = (const float*)d_in[11];
    const float* b2   = (const float*)d_in[12];
    const float* g1   = (const float*)d_in[13];
    const float* be1  = (const float*)d_in[14];
    const float* g2   = (const float*)d_in[15];
    const float* be2  = (const float*)d_in[16];
    const float* fcw  = (const float*)d_in[17];
    const float* fcb  = (const float*)d_in[18];

    float* out = (float*)d_out;
    float* Zb     = out;
    float* O1f    = Zb + NH;
    float* M2f    = O1f + NH;
    float* SCORES = M2f + NH;
    float* BQKV   = SCORES + SS8;                   // [L][2304]
    u16* ub   = (u16*)(BQKV + (long long)LAYERS * 2304);
    u16* Zbh  = ub;  ub += NH;
    u16* QKVh = ub;  ub += (long long)NROWS * 1536; // Q|K, ldc 1536
    u16* ATTB = ub;  ub += SS8;
    u16* Vt   = ub;  ub += NH;                      // [B][H][S]
    u16* O1h  = ub;  ub += NH;
    u16* M1h  = ub;  ub += NH;
    u16* WT   = ub;  ub += 41LL * WSZ;

    u16* ZFh = (u16*)d_ws;
    u16* EH  = ZFh + NH;
    const bool ehpath = ws_size >= (size_t)((NH + (long long)VOC * HID) * 2);

    const float scale = 1.0f / sqrtf((float)HID);
    const dim3 blk(256), blk128(128);

    embed_kernel<<<NROWS, blk, 0, stream>>>(x, emb, Zb, Zbh);
    transp_all<<<dim3(24, 24, 41), blk, 0, stream>>>(Wq, Wk, Wv, W1, W2, fcw, WT);
    pack_bias_all<<<dim3(3, LAYERS), dim3(768), 0, stream>>>(bq, bk, bv, BQKV);
    if (ehpath) convert_emb<<<7500, blk, 0, stream>>>(emb, EH);

    for (int l = 0; l < LAYERS; ++l) {
        const u16* wl = WT + (long long)l * 5 * WSZ;

        // qkv: Q,K -> QKVh[4096][1536]; V -> Vt transposed. big config.
        gemm_mfma<128,128,2,2, false, true, false, true><<<dim3(18, 32), blk, 0, stream>>>(
            Zbh, HID, 0, wl, HID, 0, QKVh, 1536, 0,
            2304, HID, BQKV + (long long)l * 2304, 1.0f, Vt);

        // scores = scale * Q @ K^T. small config, grid 512 blocks.
        gemm_mfma<64,64,2,1, false, false, false, false><<<dim3(8, 8, BATCH), blk128, 0, stream>>>(
            QKVh, 1536, (long long)SEQ * 1536,
            QKVh + 768, 1536, (long long)SEQ * 1536,
            SCORES, SEQ, (long long)SEQ * SEQ,
            SEQ, HID, nullptr, scale, nullptr);

        softmax_q_kernel<<<dim3(BATCH, SEQ/16), blk, 0, stream>>>(SCORES, ATTB, lens);

        // attnout = att @ V. small config, 768 blocks.
        gemm_mfma<64,64,2,1, false, false, false, false><<<dim3(12, 8, BATCH), blk128, 0, stream>>>(
            ATTB, SEQ, (long long)SEQ * SEQ,
            Vt, SEQ, (long long)HID * SEQ,
            O1f, HID, (long long)SEQ * HID,
            HID, SEQ, nullptr, 1.0f, nullptr);

        ln_add_kernel<<<NROWS, blk, 0, stream>>>(Zb, O1f, O1f, O1h,
                                                 g1 + l*HID, be1 + l*HID);
        gemm_mfma<64,64,2,1, true, true, false, false><<<dim3(12, 64), blk128, 0, stream>>>(
            O1h, HID, 0, wl + 3*WSZ, HID, 0, M1h, HID, 0,
            HID, HID, b1 + l*HID, 1.0f, nullptr);
        gemm_mfma<64,64,2,1, false, false, false, false><<<dim3(12, 64), blk128, 0, stream>>>(
            M1h, HID, 0, wl + 4*WSZ, HID, 0, M2f, HID, 0,
            HID, HID, b2 + l*HID, 1.0f, nullptr);
        ln_add_kernel<<<NROWS, blk, 0, stream>>>(M2f, O1f, Zb, Zbh,
                                                 g2 + l*HID, be2 + l*HID);
    }

    gemm_mfma<64,64,2,1, false, true, false, false><<<dim3(12, 64), blk128, 0, stream>>>(
        Zbh, HID, 0, WT + 40LL*WSZ, HID, 0, ZFh, HID, 0,
        HID, HID, fcb, 1.0f, nullptr);

    if (ehpath) {
        gemm_mfma<128,128,2,2, false, false, true, false><<<dim3(32, 79), blk, 0, stream>>>(
            ZFh, HID, 0, EH, HID, 0, out, VOC, 0,
            VOC, HID, nullptr, 1.0f, nullptr);
    } else {
        gemm_conv<<<dim3(32, 79), blk, 0, stream>>>(ZFh, emb, out);
    }

    softmax_v_kernel<<<NROWS, blk, 0, stream>>>(out);
}

// Round 6
// 1095.162 us; speedup vs baseline: 5.9135x; 1.1392x over previous
//
#include <hip/hip_runtime.h>
#include <math.h>

typedef unsigned int   u32;
typedef unsigned short u16;
typedef __attribute__((ext_vector_type(8))) short bf16x8;
typedef __attribute__((ext_vector_type(4))) float f32x4;
typedef __attribute__((ext_vector_type(4))) unsigned short u16x4;
typedef __attribute__((ext_vector_type(8))) unsigned short u16x8;

#define HID   768
#define SEQ   512
#define BATCH 8
#define LAYERS 8
#define VOC   10000
#define NROWS (BATCH*SEQ)             // 4096
#define NH    ((long long)NROWS*HID)  // 3,145,728
#define SS8   ((long long)BATCH*SEQ*SEQ)
#define EPSLN 1e-5f
#define WSZ   ((long long)HID*HID)    // 589824

__device__ __forceinline__ u16 f2bf(float f) {
    u32 u = __builtin_bit_cast(u32, f);
    return (u16)((u + 0x7fffu + ((u >> 16) & 1u)) >> 16);
}
__device__ __forceinline__ float bf2f(u16 h) {
    return __builtin_bit_cast(float, (u32)h << 16);
}

__device__ __forceinline__ void async16(u16* lds, const u16* g) {
    __builtin_amdgcn_global_load_lds(
        (const __attribute__((address_space(1))) u32*)g,
        (__attribute__((address_space(3))) u32*)lds, 16, 0, 0);
}

// ---- embedding + positional encoding (fp32 + bf16 shadow) ---------------
__global__ __launch_bounds__(256) void embed_kernel(
    const int* __restrict__ x, const float* __restrict__ emb,
    float* __restrict__ Z, u16* __restrict__ Zh)
{
    const int row = blockIdx.x;
    const int s   = row & (SEQ - 1);
    const int tok = x[row];
    const long long base  = (long long)row * HID;
    const long long ebase = (long long)tok * HID;
    const float coef = -0.0239852613853544f;   // -2*ln(10000)/768
    #pragma unroll
    for (int j = 0; j < 3; ++j) {
        const int h = threadIdx.x + 256 * j;
        const int i = h >> 1;
        const float ang = (float)s * expf((float)i * coef);
        const float pe  = (h & 1) ? cosf(ang) : sinf(ang);
        const float v = emb[ebase + h] + pe;
        Z[base + h]  = v;
        Zh[base + h] = f2bf(v);
    }
}

// ---- emb fp32 -> bf16, vectorized --------------------------------------
__global__ __launch_bounds__(256) void convert_emb(
    const float* __restrict__ e, u16* __restrict__ eh)
{
    const long long i = ((long long)blockIdx.x * 256 + threadIdx.x) * 4;
    const float4 v = *(const float4*)&e[i];
    u16x4 p;
    p[0] = f2bf(v.x); p[1] = f2bf(v.y); p[2] = f2bf(v.z); p[3] = f2bf(v.w);
    *(u16x4*)&eh[i] = p;
}

// ---- all-weights transpose+convert: fp32 [K,N] -> bf16 [N,K] ------------
__global__ __launch_bounds__(256) void transp_all(
    const float* __restrict__ Wq, const float* __restrict__ Wk,
    const float* __restrict__ Wv, const float* __restrict__ W1,
    const float* __restrict__ W2, const float* __restrict__ fcw,
    u16* __restrict__ WT)
{
    __shared__ u16 tile[32][34];
    const int z = blockIdx.z;
    const float* src;
    long long doff;
    if (z < 40) {
        const int lyr = z / 5, idx = z % 5;
        const float* bases[5] = {Wq, Wk, Wv, W1, W2};
        src  = bases[idx] + (long long)lyr * WSZ;
        doff = ((long long)lyr * 5 + idx) * WSZ;
    } else {
        src = fcw; doff = 40LL * WSZ;
    }
    u16* D = WT + doff;
    const int n0 = blockIdx.x * 32, k0 = blockIdx.y * 32;
    const int c = threadIdx.x & 31, r0 = threadIdx.x >> 5;
    #pragma unroll
    for (int p = 0; p < 4; ++p)
        tile[r0 + 8*p][c] = f2bf(src[(long long)(k0 + r0 + 8*p) * HID + n0 + c]);
    __syncthreads();
    #pragma unroll
    for (int p = 0; p < 4; ++p)
        D[(long long)(n0 + r0 + 8*p) * HID + k0 + c] = tile[c][r0 + 8*p];
}

// ---- pack qkv biases: [L][3*768] ---------------------------------------
__global__ void pack_bias_all(const float* __restrict__ bq,
                              const float* __restrict__ bk,
                              const float* __restrict__ bv,
                              float* __restrict__ dst)
{
    const int part = blockIdx.x, l = blockIdx.y, h = threadIdx.x;
    const float* src = part == 0 ? bq : (part == 1 ? bk : bv);
    dst[((long long)l*3 + part) * HID + h] = src[(long long)l*HID + h];
}

// ---- big MFMA GEMM (BM=BN=128, 4 waves, BK=32, 2-buf counted vmcnt) -----
// XISM: blockIdx.x indexes M. VSPLIT: cols>=1536 written transposed to vt.
template<bool RELU, bool OUT_BF16, bool XISM, bool VSPLIT>
__global__ __launch_bounds__(256) void gemm_mfma(
    const u16* __restrict__ A, int lda, long long sA,
    const u16* __restrict__ B, int ldb, long long sB,
    void* __restrict__ Cp, int ldc, long long sC,
    int N, int K, const float* __restrict__ bias, float alpha,
    u16* __restrict__ vt)
{
    __shared__ u16 As[2][128 * 32];
    __shared__ u16 Bs[2][128 * 32];
    const int bz = blockIdx.z;
    const int m0 = (XISM ? blockIdx.x : blockIdx.y) * 128;
    const int n0 = (XISM ? blockIdx.y : blockIdx.x) * 128;
    const int t = threadIdx.x, w = t >> 6, l = t & 63;
    const int lrow = l >> 2, lk8 = (l & 3) * 8;
    const int wm = (w >> 1) * 64, wn = (w & 1) * 64;
    A += sA * bz; B += sB * bz;

    f32x4 acc[4][4];
    #pragma unroll
    for (int mi = 0; mi < 4; ++mi)
        #pragma unroll
        for (int ni = 0; ni < 4; ++ni) acc[mi][ni] = (f32x4){0.f,0.f,0.f,0.f};

    auto stage = [&](int buf, int k0) {
        #pragma unroll
        for (int r = 0; r < 2; ++r) {
            const int seg = w * 2 + r;
            async16(&As[buf][seg * 512],
                    A + (long long)(m0 + seg*16 + lrow) * lda + (k0 + lk8));
        }
        #pragma unroll
        for (int r = 0; r < 2; ++r) {
            const int seg = w * 2 + r;
            int row = n0 + seg*16 + lrow;
            row = row < N ? row : N - 1;
            async16(&Bs[buf][seg * 512], B + (long long)row * ldb + (k0 + lk8));
        }
    };
    const int fr = l & 15, fk = (l >> 4) * 8;
    auto compute = [&](int cur) {
        bf16x8 af[4], bfr[4];
        #pragma unroll
        for (int mi = 0; mi < 4; ++mi)
            af[mi] = *(const bf16x8*)&As[cur][(wm + mi*16 + fr) * 32 + fk];
        #pragma unroll
        for (int ni = 0; ni < 4; ++ni)
            bfr[ni] = *(const bf16x8*)&Bs[cur][(wn + ni*16 + fr) * 32 + fk];
        #pragma unroll
        for (int mi = 0; mi < 4; ++mi)
            #pragma unroll
            for (int ni = 0; ni < 4; ++ni)
                acc[mi][ni] = __builtin_amdgcn_mfma_f32_16x16x32_bf16(
                    af[mi], bfr[ni], acc[mi][ni], 0, 0, 0);
    };

    const int NS = K >> 5;
    stage(0, 0);
    for (int tt = 0; tt < NS; ++tt) {
        if (tt + 1 < NS) {
            stage((tt + 1) & 1, (tt + 1) << 5);
            asm volatile("s_waitcnt vmcnt(4)\n\ts_barrier" ::: "memory");
        } else {
            asm volatile("s_waitcnt vmcnt(0)\n\ts_barrier" ::: "memory");
        }
        compute(tt & 1);
        asm volatile("s_barrier" ::: "memory");
    }

    float* Cf = (float*)Cp + sC * bz;
    u16*   Ch = (u16*)Cp + sC * bz;
    const int fq = l >> 4;
    #pragma unroll
    for (int ni = 0; ni < 4; ++ni) {
        const int col = n0 + wn + ni*16 + fr;
        const bool ok = col < N;
        const float bv = (bias && ok) ? bias[col] : 0.f;
        #pragma unroll
        for (int mi = 0; mi < 4; ++mi) {
            const int row0 = m0 + wm + mi*16 + fq*4;
            if constexpr (VSPLIT) {
                if (col < 1536) {
                    #pragma unroll
                    for (int v = 0; v < 4; ++v)
                        Ch[(long long)(row0 + v) * ldc + col] =
                            f2bf(alpha * acc[mi][ni][v] + bv);
                } else {
                    const int b9 = row0 >> 9, s9 = row0 & 511;
                    u16x4 pk;
                    #pragma unroll
                    for (int v = 0; v < 4; ++v)
                        pk[v] = f2bf(alpha * acc[mi][ni][v] + bv);
                    *(u16x4*)&vt[((long long)b9 * HID + (col - 1536)) * SEQ + s9] = pk;
                }
            } else {
                #pragma unroll
                for (int v = 0; v < 4; ++v) {
                    float val = alpha * acc[mi][ni][v] + bv;
                    if (RELU) val = fmaxf(val, 0.f);
                    if (ok) {
                        if (OUT_BF16) Ch[(long long)(row0 + v) * ldc + col] = f2bf(val);
                        else          Cf[(long long)(row0 + v) * ldc + col] = val;
                    }
                }
            }
        }
    }
}

// ---- small MFMA GEMM: BM=BN=64, BK=64, 2 waves, XOR-swizzled LDS --------
// Swizzle (involution, both sides): stage lane fetches global k-slot
// (l&7)^(l>>3) (LDS dest linear); reader of logical slot s at row r reads
// phys slot s^(r&7). Bank-balanced for ds_read_b128 at 128B row stride.
template<bool RELU, bool OUT_BF16>
__global__ __launch_bounds__(128) void gemm_small(
    const u16* __restrict__ A, int lda, long long sA,
    const u16* __restrict__ B, int ldb, long long sB,
    void* __restrict__ Cp, int ldc, long long sC,
    int N, int K, const float* __restrict__ bias, float alpha)
{
    __shared__ u16 As[2][64 * 64];
    __shared__ u16 Bs[2][64 * 64];
    const int bz = blockIdx.z;
    const int n0 = blockIdx.x * 64;
    const int m0 = blockIdx.y * 64;
    const int t = threadIdx.x, w = t >> 6, l = t & 63;
    const int srow = l >> 3;                  // row within 8-row seg
    const int skof = ((l & 7) ^ srow) * 8;    // pre-swizzled global k-slot
    const int wm = w * 32;
    A += sA * bz; B += sB * bz;

    f32x4 acc[2][4];
    #pragma unroll
    for (int mi = 0; mi < 2; ++mi)
        #pragma unroll
        for (int ni = 0; ni < 4; ++ni) acc[mi][ni] = (f32x4){0.f,0.f,0.f,0.f};

    auto stage = [&](int buf, int k0) {
        #pragma unroll
        for (int r = 0; r < 4; ++r) {
            const int seg = w * 4 + r;
            const int row = seg * 8 + srow;
            async16(&As[buf][seg * 512],
                    A + (long long)(m0 + row) * lda + (k0 + skof));
        }
        #pragma unroll
        for (int r = 0; r < 4; ++r) {
            const int seg = w * 4 + r;
            const int row = seg * 8 + srow;
            async16(&Bs[buf][seg * 512],
                    B + (long long)(n0 + row) * ldb + (k0 + skof));
        }
    };
    const int fr = l & 15, fkb = l >> 4;      // logical slot base 0..3
    auto compute = [&](int cur) {
        #pragma unroll
        for (int ks = 0; ks < 2; ++ks) {
            const int ps = ((ks * 4 + fkb) ^ (fr & 7)) * 8;
            bf16x8 af[2], bfv[4];
            #pragma unroll
            for (int mi = 0; mi < 2; ++mi)
                af[mi] = *(const bf16x8*)&As[cur][(wm + mi*16 + fr) * 64 + ps];
            #pragma unroll
            for (int ni = 0; ni < 4; ++ni)
                bfv[ni] = *(const bf16x8*)&Bs[cur][(ni*16 + fr) * 64 + ps];
            #pragma unroll
            for (int mi = 0; mi < 2; ++mi)
                #pragma unroll
                for (int ni = 0; ni < 4; ++ni)
                    acc[mi][ni] = __builtin_amdgcn_mfma_f32_16x16x32_bf16(
                        af[mi], bfv[ni], acc[mi][ni], 0, 0, 0);
        }
    };

    const int NS = K >> 6;                    // 12 (K=768) or 8 (K=512)
    stage(0, 0);
    for (int tt = 0; tt < NS; ++tt) {
        if (tt + 1 < NS) {
            stage((tt + 1) & 1, (tt + 1) << 6);
            asm volatile("s_waitcnt vmcnt(8)\n\ts_barrier" ::: "memory");
        } else {
            asm volatile("s_waitcnt vmcnt(0)\n\ts_barrier" ::: "memory");
        }
        compute(tt & 1);
        asm volatile("s_barrier" ::: "memory");
    }

    float* Cf = (float*)Cp + sC * bz;
    u16*   Ch = (u16*)Cp + sC * bz;
    const int fq = l >> 4;
    #pragma unroll
    for (int ni = 0; ni < 4; ++ni) {
        const int col = n0 + ni*16 + fr;
        const float bv = bias ? bias[col] : 0.f;
        #pragma unroll
        for (int mi = 0; mi < 2; ++mi) {
            const int row0 = m0 + wm + mi*16 + fq*4;
            #pragma unroll
            for (int v = 0; v < 4; ++v) {
                float val = alpha * acc[mi][ni][v] + bv;
                if (RELU) val = fmaxf(val, 0.f);
                if (OUT_BF16) Ch[(long long)(row0 + v) * ldc + col] = f2bf(val);
                else          Cf[(long long)(row0 + v) * ldc + col] = val;
            }
        }
    }
}

// ---- fallback logits GEMM (fp32 B converted in-flight) -> bf16 out ------
__global__ __launch_bounds__(256) void gemm_conv(
    const u16* __restrict__ A, const float* __restrict__ Bf,
    u16* __restrict__ C)  // C = (u16*)out + VOC, ldc 2*VOC
{
    __shared__ u16 As[128 * 32];
    __shared__ u16 Bs[128 * 32];
    const int m0 = blockIdx.x * 128;
    const int n0 = blockIdx.y * 128;
    const int t = threadIdx.x, w = t >> 6, l = t & 63;
    const int lrow = l >> 2, lk8 = (l & 3) * 8;
    const int wm = (w >> 1) * 64, wn = (w & 1) * 64;
    f32x4 acc[4][4];
    #pragma unroll
    for (int mi = 0; mi < 4; ++mi)
        #pragma unroll
        for (int ni = 0; ni < 4; ++ni) acc[mi][ni] = (f32x4){0.f,0.f,0.f,0.f};

    for (int k0 = 0; k0 < HID; k0 += 32) {
        #pragma unroll
        for (int r = 0; r < 2; ++r) {
            const int seg = w * 2 + r;
            async16(&As[seg * 512],
                    A + (long long)(m0 + seg*16 + lrow) * HID + (k0 + lk8));
        }
        #pragma unroll
        for (int r = 0; r < 2; ++r) {
            const int flat = r * 2048 + t * 8;
            int row = n0 + (flat >> 5);
            row = row < VOC ? row : VOC - 1;
            const float* g = Bf + (long long)row * HID + (k0 + (flat & 31));
            const float4 v0 = *(const float4*)g;
            const float4 v1 = *(const float4*)(g + 4);
            bf16x8 hv;
            hv[0]=(short)f2bf(v0.x); hv[1]=(short)f2bf(v0.y);
            hv[2]=(short)f2bf(v0.z); hv[3]=(short)f2bf(v0.w);
            hv[4]=(short)f2bf(v1.x); hv[5]=(short)f2bf(v1.y);
            hv[6]=(short)f2bf(v1.z); hv[7]=(short)f2bf(v1.w);
            *(bf16x8*)&Bs[flat] = hv;
        }
        __syncthreads();
        const int fr = l & 15, fk = (l >> 4) * 8;
        bf16x8 af[4], bfr[4];
        #pragma unroll
        for (int mi = 0; mi < 4; ++mi)
            af[mi] = *(const bf16x8*)&As[(wm + mi*16 + fr) * 32 + fk];
        #pragma unroll
        for (int ni = 0; ni < 4; ++ni)
            bfr[ni] = *(const bf16x8*)&Bs[(wn + ni*16 + fr) * 32 + fk];
        #pragma unroll
        for (int mi = 0; mi < 4; ++mi)
            #pragma unroll
            for (int ni = 0; ni < 4; ++ni)
                acc[mi][ni] = __builtin_amdgcn_mfma_f32_16x16x32_bf16(
                    af[mi], bfr[ni], acc[mi][ni], 0, 0, 0);
        __syncthreads();
    }
    const int fr = l & 15, fq = l >> 4;
    #pragma unroll
    for (int ni = 0; ni < 4; ++ni) {
        const int col = n0 + wn + ni*16 + fr;
        if (col >= VOC) continue;
        #pragma unroll
        for (int mi = 0; mi < 4; ++mi) {
            const int row0 = m0 + wm + mi*16 + fq*4;
            #pragma unroll
            for (int v = 0; v < 4; ++v)
                C[(long long)(row0 + v) * (2*VOC) + col] = f2bf(acc[mi][ni][v]);
        }
    }
}

// ---- masked softmax over QUERY axis (dim=1): fp32 in, bf16 out ----------
// block 256 = 16 q-slices x 16 cols; grid (BATCH, SEQ/16). Values cached
// in registers (static 32-deep unroll) to skip the 2nd global read.
__global__ __launch_bounds__(256) void softmax_q_kernel(
    const float* __restrict__ sc, u16* __restrict__ att,
    const int* __restrict__ lengths)
{
    const int b  = blockIdx.x;
    const int k0 = blockIdx.y * 16;
    const int tx = threadIdx.x & 15;
    const int ty = threadIdx.x >> 4;
    const int c  = k0 + tx;
    const int len = lengths[b];
    const float* base  = sc  + (long long)b * SEQ * SEQ;
    u16*         obase = att + (long long)b * SEQ * SEQ;
    const bool cvalid = (c < len);

    float vals[32];
    float m = -3.0e38f, ssum = 0.f;
    #pragma unroll
    for (int i = 0; i < 32; ++i) {
        const int q = ty + 16 * i;
        float xv = -3.0e38f;
        if (cvalid && c <= q && q < len)
            xv = base[(long long)q * SEQ + c];
        vals[i] = xv;
        if (xv > m) { ssum = ssum * __expf(m - xv) + 1.f; m = xv; }
        else if (xv > -3.0e38f) { ssum += __expf(xv - m); }
    }
    __shared__ float ms[16][17], ss[16][17];
    ms[ty][tx] = m; ss[ty][tx] = ssum;
    __syncthreads();
    if (ty == 0) {
        float M = ms[0][tx];
        #pragma unroll
        for (int r = 1; r < 16; ++r) M = fmaxf(M, ms[r][tx]);
        float Sx = 0.f;
        #pragma unroll
        for (int r = 0; r < 16; ++r) Sx += ss[r][tx] * __expf(ms[r][tx] - M);
        ms[0][tx] = M; ss[0][tx] = Sx;
    }
    __syncthreads();
    const float M   = ms[0][tx];
    const float den = ss[0][tx];
    const float inv = (den > 0.f) ? 1.f / den : 0.f;
    #pragma unroll
    for (int i = 0; i < 32; ++i) {
        const int q = ty + 16 * i;
        obase[(long long)q * SEQ + c] = f2bf(__expf(vals[i] - M) * inv);
    }
}

// ---- fused residual-add + LayerNorm, fp32 + bf16 outputs ---------------
__global__ __launch_bounds__(256) void ln_add_kernel(
    const float* __restrict__ Xa, const float* __restrict__ Xb,
    float* __restrict__ O, u16* __restrict__ Oh,
    const float* __restrict__ g, const float* __restrict__ be)
{
    const int row = blockIdx.x;
    const long long base = (long long)row * HID;
    const int t = threadIdx.x;
    const float x0 = Xa[base + t]       + Xb[base + t];
    const float x1 = Xa[base + t + 256] + Xb[base + t + 256];
    const float x2 = Xa[base + t + 512] + Xb[base + t + 512];
    __shared__ float r1[4], r2[4];
    float s = x0 + x1 + x2;
    #pragma unroll
    for (int o = 32; o; o >>= 1) s += __shfl_down(s, o, 64);
    if ((t & 63) == 0) r1[t >> 6] = s;
    __syncthreads();
    const float mean = (r1[0] + r1[1] + r1[2] + r1[3]) * (1.f / HID);
    const float d0 = x0 - mean, d1 = x1 - mean, d2 = x2 - mean;
    float v = d0*d0 + d1*d1 + d2*d2;
    #pragma unroll
    for (int o = 32; o; o >>= 1) v += __shfl_down(v, o, 64);
    if ((t & 63) == 0) r2[t >> 6] = v;
    __syncthreads();
    const float var = (r2[0] + r2[1] + r2[2] + r2[3]) * (1.f / HID);
    const float rs = rsqrtf(var + EPSLN);
    const float y0 = d0 * rs * g[t]       + be[t];
    const float y1 = d1 * rs * g[t + 256] + be[t + 256];
    const float y2 = d2 * rs * g[t + 512] + be[t + 512];
    O[base + t]        = y0;  Oh[base + t]       = f2bf(y0);
    O[base + t + 256]  = y1;  Oh[base + t + 256] = f2bf(y1);
    O[base + t + 512]  = y2;  Oh[base + t + 512] = f2bf(y2);
}

// ---- vocab softmax: bf16 logits in (row-local upper half), fp32 out -----
__global__ __launch_bounds__(256) void softmax_v_kernel(float* __restrict__ out)
{
    __shared__ float row[VOC];            // 40 KB
    __shared__ float rm[4], rs_[4];
    const long long obase = (long long)blockIdx.x * VOC;
    const u16* lg = (const u16*)out + 2 * obase + VOC;  // bf16 logits row
    const int t = threadIdx.x;
    float m = -3.0e38f, s = 0.f;
    for (int i = t * 8; i < VOC; i += 2048) {
        const u16x8 h8 = *(const u16x8*)&lg[i];
        #pragma unroll
        for (int j = 0; j < 8; ++j) {
            const float xv = bf2f(h8[j]);
            row[i + j] = xv;
            const float d = xv - m;
            if (d > 0.f) { s = s * __expf(-d) + 1.f; m = xv; }
            else         { s += __expf(d); }
        }
    }
    #pragma unroll
    for (int o = 32; o; o >>= 1) {
        const float om = __shfl_down(m, o, 64), os = __shfl_down(s, o, 64);
        const float M = fmaxf(m, om);
        s = s * __expf(m - M) + os * __expf(om - M);
        m = M;
    }
    if ((t & 63) == 0) { rm[t >> 6] = m; rs_[t >> 6] = s; }
    __syncthreads();
    const float M = fmaxf(fmaxf(rm[0], rm[1]), fmaxf(rm[2], rm[3]));
    const float S = rs_[0]*__expf(rm[0]-M) + rs_[1]*__expf(rm[1]-M)
                  + rs_[2]*__expf(rm[2]-M) + rs_[3]*__expf(rm[3]-M);
    const float inv = 1.f / S;
    for (int i = t * 4; i < VOC; i += 1024) {
        float4 v = *(const float4*)&row[i];
        v.x = __expf(v.x - M) * inv;
        v.y = __expf(v.y - M) * inv;
        v.z = __expf(v.z - M) * inv;
        v.w = __expf(v.w - M) * inv;
        *(float4*)&out[obase + i] = v;
    }
}

// ---- host-side orchestration -------------------------------------------
extern "C" void kernel_launch(void* const* d_in, const int* in_sizes, int n_in,
                              void* d_out, int out_size, void* d_ws, size_t ws_size,
                              hipStream_t stream)
{
    const int*   x    = (const int*)  d_in[0];
    const int*   lens = (const int*)  d_in[1];
    const float* emb  = (const float*)d_in[2];
    const float* Wq   = (const float*)d_in[3];
    const float* bq   = (const float*)d_in[4];
    const float* Wk   = (const float*)d_in[5];
    const float* bk   = (const float*)d_in[6];
    const float* Wv   = (const float*)d_in[7];
    const float* bv   = (const float*)d_in[8];
    const float* W1   = (const float*)d_in[9];
    const float* b1   = (const float*)d_in[10];
    const float* W2   = (const float*)d_in[11];
    const float* b2   = (const float*)d_in[12];
    const float* g1   = (const float*)d_in[13];
    const float* be1  = (const float*)d_in[14];
    const float* g2   = (const float*)d_in[15];
    const float* be2  = (const float*)d_in[16];
    const float* fcw  = (const float*)d_in[17];
    const float* fcb  = (const float*)d_in[18];

    float* out = (float*)d_out;
    float* Zb     = out;
    float* O1f    = Zb + NH;
    float* M2f    = O1f + NH;
    float* SCORES = M2f + NH;
    float* BQKV   = SCORES + SS8;                   // [L][2304]
    u16* ub   = (u16*)(BQKV + (long long)LAYERS * 2304);
    u16* Zbh  = ub;  ub += NH;
    u16* QKVh = ub;  ub += (long long)NROWS * 1536; // Q|K, ldc 1536
    u16* ATTB = ub;  ub += SS8;
    u16* Vt   = ub;  ub += NH;                      // [B][H][S]
    u16* O1h  = ub;  ub += NH;
    u16* M1h  = ub;  ub += NH;
    u16* WT   = ub;  ub += 41LL * WSZ;

    u16* ZFh = (u16*)d_ws;
    u16* EH  = ZFh + NH;
    const bool ehpath = ws_size >= (size_t)((NH + (long long)VOC * HID) * 2);
    // bf16 logits: row i lives in the 2nd half of output row i's own slot
    u16* LOGH = (u16*)out + VOC;                    // ldc = 2*VOC

    const float scale = 1.0f / sqrtf((float)HID);
    const dim3 blk(256), blk128(128);

    embed_kernel<<<NROWS, blk, 0, stream>>>(x, emb, Zb, Zbh);
    transp_all<<<dim3(24, 24, 41), blk, 0, stream>>>(Wq, Wk, Wv, W1, W2, fcw, WT);
    pack_bias_all<<<dim3(3, LAYERS), dim3(768), 0, stream>>>(bq, bk, bv, BQKV);
    if (ehpath) convert_emb<<<7500, blk, 0, stream>>>(emb, EH);

    for (int l = 0; l < LAYERS; ++l) {
        const u16* wl = WT + (long long)l * 5 * WSZ;

        // qkv: Q,K -> QKVh[4096][1536]; V -> Vt transposed. big config.
        gemm_mfma<false, true, false, true><<<dim3(18, 32), blk, 0, stream>>>(
            Zbh, HID, 0, wl, HID, 0, QKVh, 1536, 0,
            2304, HID, BQKV + (long long)l * 2304, 1.0f, Vt);

        // scores = scale * Q @ K^T
        gemm_small<false, false><<<dim3(8, 8, BATCH), blk128, 0, stream>>>(
            QKVh, 1536, (long long)SEQ * 1536,
            QKVh + 768, 1536, (long long)SEQ * 1536,
            SCORES, SEQ, (long long)SEQ * SEQ,
            512, HID, nullptr, scale);

        softmax_q_kernel<<<dim3(BATCH, SEQ/16), blk, 0, stream>>>(SCORES, ATTB, lens);

        // attnout = att @ V
        gemm_small<false, false><<<dim3(12, 8, BATCH), blk128, 0, stream>>>(
            ATTB, SEQ, (long long)SEQ * SEQ,
            Vt, SEQ, (long long)HID * SEQ,
            O1f, HID, (long long)SEQ * HID,
            768, SEQ, nullptr, 1.0f);

        ln_add_kernel<<<NROWS, blk, 0, stream>>>(Zb, O1f, O1f, O1h,
                                                 g1 + l*HID, be1 + l*HID);
        gemm_small<true, true><<<dim3(12, 64), blk128, 0, stream>>>(
            O1h, HID, 0, wl + 3*WSZ, HID, 0, M1h, HID, 0,
            768, HID, b1 + l*HID, 1.0f);
        gemm_small<false, false><<<dim3(12, 64), blk128, 0, stream>>>(
            M1h, HID, 0, wl + 4*WSZ, HID, 0, M2f, HID, 0,
            768, HID, b2 + l*HID, 1.0f);
        ln_add_kernel<<<NROWS, blk, 0, stream>>>(M2f, O1f, Zb, Zbh,
                                                 g2 + l*HID, be2 + l*HID);
    }

    // fc: zf = z @ fc_w + fc_b -> bf16 in d_ws
    gemm_small<false, true><<<dim3(12, 64), blk128, 0, stream>>>(
        Zbh, HID, 0, WT + 40LL*WSZ, HID, 0, ZFh, HID, 0,
        768, HID, fcb, 1.0f);

    // logits = zf @ emb^T -> bf16, row-local upper half of d_out
    if (ehpath) {
        gemm_mfma<false, true, true, false><<<dim3(32, 79), blk, 0, stream>>>(
            ZFh, HID, 0, EH, HID, 0, LOGH, 2*VOC, 0,
            VOC, HID, nullptr, 1.0f, nullptr);
    } else {
        gemm_conv<<<dim3(32, 79), blk, 0, stream>>>(ZFh, emb, LOGH);
    }

    softmax_v_kernel<<<NROWS, blk, 0, stream>>>(out);
}